// Round 8
// baseline (1298.648 us; speedup 1.0000x reference)
//
#include <hip/hip_runtime.h>

// Problem constants (match reference setup_inputs)
constexpr int N_NODES = 50000;
constexpr int N_EDGES = 800000;
constexpr int N_ETOT  = N_EDGES + N_NODES;   // with self loops
constexpr int HID     = 128;
constexpr int HEADS   = 4;
constexpr int ED      = 12;
constexpr int LAYERS  = 4;
constexpr float BN_EPS = 1e-5f;
constexpr int SCAN_BLK = (N_NODES + 255) / 256;   // 196
constexpr int NBUCKET  = SCAN_BLK;                // bucket = dst >> 8

typedef __attribute__((ext_vector_type(8))) short short8;
typedef __attribute__((ext_vector_type(4))) float floatx4;

__device__ inline unsigned bf16pair(float a, float b) {
    unsigned ua = __float_as_uint(a), ub = __float_as_uint(b);
    ua = (ua + 0x7FFFu + ((ua >> 16) & 1u)) >> 16;
    ub = (ub + 0x7FFFu + ((ub >> 16) & 1u)) >> 16;
    return ua | (ub << 16);
}

// ---------------------------------------------------------------------------
// CSR build, bucketed for write locality.
//  hist2: node-degree histogram + bucket histogram (LDS-aggregated)
//  bscan2: exclusive scan of bucket counts -> bbase, bcursor
//  bfill: append packed (dst|src|eid) u64 to bucket region
//  cscatter: walk buckets in order; final pos via cursor[dst]; writes land in
//            a ~35 KB window per block -> L2-friendly.
// ---------------------------------------------------------------------------
__global__ void hist2_kernel(const int* __restrict__ dst, int* __restrict__ hist,
                             int* __restrict__ bcnt) {
    __shared__ int bl[NBUCKET];
    int t = threadIdx.x;
    for (int i = t; i < NBUCKET; i += 256) bl[i] = 0;
    __syncthreads();
    int e = blockIdx.x * 256 + t;
    if (e < N_ETOT) {
        int d = (e < N_EDGES) ? dst[e] : (e - N_EDGES);
        atomicAdd(&hist[d], 1);
        atomicAdd(&bl[d >> 8], 1);
    }
    __syncthreads();
    for (int i = t; i < NBUCKET; i += 256)
        if (bl[i]) atomicAdd(&bcnt[i], bl[i]);
}

__global__ void bscan2_kernel(const int* __restrict__ bcnt, int* __restrict__ bbase,
                              int* __restrict__ bcursor) {
    __shared__ int sd[256];
    int t = threadIdx.x;
    int v = (t < NBUCKET) ? bcnt[t] : 0;
    sd[t] = v;
    __syncthreads();
#pragma unroll
    for (int off = 1; off < 256; off <<= 1) {
        int u = (t >= off) ? sd[t - off] : 0;
        __syncthreads();
        sd[t] += u;
        __syncthreads();
    }
    if (t < NBUCKET) {
        int excl = sd[t] - v;
        bbase[t] = excl;
        bcursor[t] = excl;
    }
}

__global__ void bfill_kernel(const int* __restrict__ src, const int* __restrict__ dst,
                             int* __restrict__ bcursor, unsigned long long* __restrict__ bpk) {
    int e = blockIdx.x * 256 + threadIdx.x;
    if (e >= N_ETOT) return;
    int s, d;
    if (e < N_EDGES) { s = src[e]; d = dst[e]; }
    else             { s = d = e - N_EDGES; }
    int pos = atomicAdd(&bcursor[d >> 8], 1);
    bpk[pos] = ((unsigned long long)(unsigned)d << 36) |
               ((unsigned long long)(unsigned)s << 20) | (unsigned)e;
}

__global__ void cscatter_kernel(const unsigned long long* __restrict__ bpk,
                                int* __restrict__ cursor, int2* __restrict__ csr) {
    int i = blockIdx.x * 256 + threadIdx.x;
    if (i >= N_ETOT) return;
    unsigned long long pk = bpk[i];
    int d = (int)(pk >> 36);
    int s = (int)(pk >> 20) & 0xFFFF;
    int e = (int)pk & 0xFFFFF;
    int pos = atomicAdd(&cursor[d], 1);
    csr[pos] = make_int2(s, e);
}

// ---------------------------------------------------------------------------
// Node-degree scan -> rowp, cursor
// ---------------------------------------------------------------------------
__global__ void blocksum_kernel(const int* __restrict__ hist, int* __restrict__ bsum) {
    __shared__ int sd[256];
    int t = threadIdx.x;
    int n = blockIdx.x * 256 + t;
    sd[t] = (n < N_NODES) ? hist[n] : 0;
    __syncthreads();
#pragma unroll
    for (int off = 128; off; off >>= 1) {
        if (t < off) sd[t] += sd[t + off];
        __syncthreads();
    }
    if (t == 0) bsum[blockIdx.x] = sd[0];
}

__global__ void bscan_kernel(const int* __restrict__ bsum, int* __restrict__ boff,
                             int* __restrict__ rowp) {
    __shared__ int sd[256];
    int t = threadIdx.x;
    int v = (t < SCAN_BLK) ? bsum[t] : 0;
    sd[t] = v;
    __syncthreads();
#pragma unroll
    for (int off = 1; off < 256; off <<= 1) {
        int u = (t >= off) ? sd[t - off] : 0;
        __syncthreads();
        sd[t] += u;
        __syncthreads();
    }
    if (t < SCAN_BLK) boff[t] = sd[t] - v;
    if (t == 255) rowp[N_NODES] = sd[255];
}

__global__ void rowp_kernel(const int* __restrict__ hist, const int* __restrict__ boff,
                            int* __restrict__ rowp, int* __restrict__ cursor) {
    __shared__ int sd[256];
    int t = threadIdx.x;
    int n = blockIdx.x * 256 + t;
    int v = (n < N_NODES) ? hist[n] : 0;
    sd[t] = v;
    __syncthreads();
#pragma unroll
    for (int off = 1; off < 256; off <<= 1) {
        int u = (t >= off) ? sd[t - off] : 0;
        __syncthreads();
        sd[t] += u;
        __syncthreads();
    }
    if (n < N_NODES) {
        int excl = sd[t] - v + boff[blockIdx.x];
        rowp[n] = excl;
        cursor[n] = excl;
    }
}

// ---------------------------------------------------------------------------
// edge_attr mean (over real edges) -> easum[12]
// ---------------------------------------------------------------------------
__launch_bounds__(256)
__global__ void eamean_kernel(const float* __restrict__ ea, float* __restrict__ easum) {
    __shared__ float ls[12];
    int t = threadIdx.x;
    if (t < 12) ls[t] = 0.f;
    __syncthreads();
    float loc[12];
#pragma unroll
    for (int d = 0; d < 12; d++) loc[d] = 0.f;
    int stride = gridDim.x * 256;
    for (int e = blockIdx.x * 256 + t; e < N_EDGES; e += stride) {
        const float* er = ea + (size_t)e * ED;
#pragma unroll
        for (int d = 0; d < 12; d++) loc[d] += er[d];
    }
#pragma unroll
    for (int d = 0; d < 12; d++) atomicAdd(&ls[d], loc[d]);
    __syncthreads();
    if (t < 12) atomicAdd(&easum[t], ls[t]);
}

__global__ void prep_kernel(const float* __restrict__ easum, const float* __restrict__ We,
                            const float* __restrict__ att_edge, float* __restrict__ wea_all,
                            float* __restrict__ aloop) {
    __shared__ float em[12];
    __shared__ float weash[LAYERS * ED * HEADS];
    int t = threadIdx.x;
    if (t < 12) em[t] = easum[t] / (float)N_EDGES;
    if (t < LAYERS * ED * HEADS) {
        int l = t / (ED * HEADS);
        int r = t % (ED * HEADS);
        int d = r / HEADS;
        int h = r % HEADS;
        float sum = 0.f;
#pragma unroll
        for (int c = 0; c < 32; c++)
            sum += We[((size_t)(l * ED + d)) * HID + h * 32 + c] *
                   att_edge[(l * HEADS + h) * 32 + c];
        wea_all[t] = sum;
        weash[t] = sum;
    }
    __syncthreads();
    if (t < LAYERS * HEADS) {
        int l = t / HEADS, h = t % HEADS;
        float s = 0.f;
#pragma unroll
        for (int d = 0; d < 12; d++) s += em[d] * weash[l * ED * HEADS + d * HEADS + h];
        aloop[t] = s;
    }
}

// ---------------------------------------------------------------------------
// Pack all layer weights W[l][k][n] (f32) into per-lane MFMA B-fragment order.
// ---------------------------------------------------------------------------
__global__ void packW_kernel(const float* __restrict__ W, unsigned short* __restrict__ wb) {
    int idx = blockIdx.x * 256 + threadIdx.x;
    if (idx >= LAYERS * HID * HID) return;
    int l = idx >> 14;
    int k = (idx >> 7) & 127;
    int n = idx & 127;
    unsigned u = __float_as_uint(W[idx]);
    u = (u + 0x7FFFu + ((u >> 16) & 1u)) >> 16;
    int kt = k >> 5, q = (k & 31) >> 3, j = k & 7;
    int nt = n >> 4, c = n & 15;
    int lane = q * 16 + c;
    wb[(size_t)l * 16384 + ((size_t)(kt * 8 + nt) * 64 + lane) * 8 + j] = (unsigned short)u;
}

// ---------------------------------------------------------------------------
// Initial projection GEMM (f32 SIMD): h = relu(x @ Wp + bp); dual f32/bf16 out.
// ---------------------------------------------------------------------------
__launch_bounds__(256)
__global__ void gemm0_kernel(const float* __restrict__ A, const float* __restrict__ B,
                             const float* __restrict__ bias, float* __restrict__ C,
                             unsigned* __restrict__ Cb) {
    constexpr int K = 64;
    __shared__ float Bs[K * 128];
    int t = threadIdx.x;
    const float4* B4 = (const float4*)B;
    float4* Bs4 = (float4*)Bs;
#pragma unroll
    for (int i = t; i < K * 32; i += 256) Bs4[i] = B4[i];
    __syncthreads();

    int c0 = (t & 15) * 8;
    int r0 = (t >> 4) * 4;
    int rbase = blockIdx.x * 64 + r0;

    float acc[4][8];
#pragma unroll
    for (int j = 0; j < 4; j++)
#pragma unroll
        for (int c = 0; c < 8; c++) acc[j][c] = 0.f;

    const float4* A4 = (const float4*)A;
    int rg[4];
#pragma unroll
    for (int j = 0; j < 4; j++) rg[j] = min(rbase + j, N_NODES - 1);

    for (int kk = 0; kk < K; kk += 4) {
        float4 av[4];
#pragma unroll
        for (int j = 0; j < 4; j++) av[j] = A4[(size_t)rg[j] * (K / 4) + (kk >> 2)];
        float a_arr[4][4];
#pragma unroll
        for (int j = 0; j < 4; j++) {
            a_arr[j][0] = av[j].x; a_arr[j][1] = av[j].y;
            a_arr[j][2] = av[j].z; a_arr[j][3] = av[j].w;
        }
#pragma unroll
        for (int jj = 0; jj < 4; jj++) {
            float4 b0 = Bs4[(kk + jj) * 32 + (c0 >> 2)];
            float4 b1 = Bs4[(kk + jj) * 32 + (c0 >> 2) + 1];
#pragma unroll
            for (int j = 0; j < 4; j++) {
                float a = a_arr[j][jj];
                acc[j][0] += a * b0.x; acc[j][1] += a * b0.y;
                acc[j][2] += a * b0.z; acc[j][3] += a * b0.w;
                acc[j][4] += a * b1.x; acc[j][5] += a * b1.y;
                acc[j][6] += a * b1.z; acc[j][7] += a * b1.w;
            }
        }
    }

#pragma unroll
    for (int j = 0; j < 4; j++) {
        int r = rbase + j;
        if (r < N_NODES) {
            float o[8];
#pragma unroll
            for (int c = 0; c < 8; c++) o[c] = fmaxf(acc[j][c] + bias[c0 + c], 0.f);
            ((float4*)(C + (size_t)r * 128 + c0))[0] = make_float4(o[0], o[1], o[2], o[3]);
            ((float4*)(C + (size_t)r * 128 + c0 + 4))[0] = make_float4(o[4], o[5], o[6], o[7]);
            uint4 pk;
            pk.x = bf16pair(o[0], o[1]); pk.y = bf16pair(o[2], o[3]);
            pk.z = bf16pair(o[4], o[5]); pk.w = bf16pair(o[6], o[7]);
            ((uint4*)(Cb + (size_t)r * 64 + (c0 >> 1)))[0] = pk;
        }
    }
}

// ---------------------------------------------------------------------------
// Layer projection GEMM via MFMA bf16 + fused attention dots (see R5 notes).
// ---------------------------------------------------------------------------
__launch_bounds__(256)
__global__ void gemm_mfma_kernel(const unsigned short* __restrict__ hAb,
                                 const unsigned short* __restrict__ wb,
                                 const float* __restrict__ att_s,
                                 const float* __restrict__ att_d,
                                 unsigned* __restrict__ xpb,
                                 float* __restrict__ asrc, float* __restrict__ adst) {
    __shared__ float lds[4][16][129];
    int t = threadIdx.x;
    int w = t >> 6, lane = t & 63;
    int rbase = blockIdx.x * 64 + w * 16;
    int mrow = lane & 15, quad = lane >> 4;

    floatx4 acc[8];
#pragma unroll
    for (int nt = 0; nt < 8; nt++) acc[nt] = (floatx4){0.f, 0.f, 0.f, 0.f};

    int arow = min(rbase + mrow, N_NODES - 1);
    const short8* wb8 = (const short8*)wb;
#pragma unroll
    for (int kt = 0; kt < 4; kt++) {
        short8 afrag = *(const short8*)(hAb + (size_t)arow * 128 + kt * 32 + quad * 8);
#pragma unroll
        for (int nt = 0; nt < 8; nt++) {
            short8 bfrag = wb8[(kt * 8 + nt) * 64 + lane];
            acc[nt] = __builtin_amdgcn_mfma_f32_16x16x32_bf16(afrag, bfrag, acc[nt], 0, 0, 0);
        }
    }

    // C layout -> LDS (per-wave region; same-wave read below, no barrier)
#pragma unroll
    for (int nt = 0; nt < 8; nt++)
#pragma unroll
        for (int rr = 0; rr < 4; rr++)
            lds[w][quad * 4 + rr][nt * 16 + mrow] = acc[nt][rr];

    int row = lane >> 2, h = lane & 3;
    int r = rbase + row;
    float vals[32];
    float ps = 0.f, pd = 0.f;
#pragma unroll
    for (int c = 0; c < 32; c++) {
        float v = lds[w][row][h * 32 + c];
        vals[c] = v;
        ps += v * att_s[h * 32 + c];
        pd += v * att_d[h * 32 + c];
    }
    if (r < N_NODES) {
        unsigned* dstp = xpb + (size_t)r * 64 + h * 16;
#pragma unroll
        for (int qq = 0; qq < 4; qq++) {
            uint4 o;
            o.x = bf16pair(vals[qq * 8 + 0], vals[qq * 8 + 1]);
            o.y = bf16pair(vals[qq * 8 + 2], vals[qq * 8 + 3]);
            o.z = bf16pair(vals[qq * 8 + 4], vals[qq * 8 + 5]);
            o.w = bf16pair(vals[qq * 8 + 6], vals[qq * 8 + 7]);
            ((uint4*)dstp)[qq] = o;
        }
        asrc[r * 4 + h] = ps;
        adst[r * 4 + h] = pd;
    }
}

// ---------------------------------------------------------------------------
// Per-edge: ex = exp(leakyrelu(a_src+a_dst+a_edge)), stored COALESCED at [e].
// ---------------------------------------------------------------------------
__launch_bounds__(256)
__global__ void edge_kernel(const int* __restrict__ src, const int* __restrict__ dst,
                            const float* __restrict__ ea, const float* __restrict__ asrc,
                            const float* __restrict__ adst, const float* __restrict__ wea,
                            const float* __restrict__ aloop, float* __restrict__ exs) {
    int e = blockIdx.x * blockDim.x + threadIdx.x;
    if (e >= N_ETOT) return;
    int s, d;
    float ae0, ae1, ae2, ae3;
    if (e < N_EDGES) {
        s = src[e]; d = dst[e];
        ae0 = ae1 = ae2 = ae3 = 0.f;
        const float* er = ea + (size_t)e * ED;
#pragma unroll
        for (int dd = 0; dd < 12; dd++) {
            float v = er[dd];
            ae0 += v * wea[dd * 4 + 0];
            ae1 += v * wea[dd * 4 + 1];
            ae2 += v * wea[dd * 4 + 2];
            ae3 += v * wea[dd * 4 + 3];
        }
    } else {
        s = d = e - N_EDGES;
        ae0 = aloop[0]; ae1 = aloop[1]; ae2 = aloop[2]; ae3 = aloop[3];
    }
    float4 as = ((const float4*)asrc)[s];
    float4 ad = ((const float4*)adst)[d];
    float a0 = as.x + ad.x + ae0;
    float a1 = as.y + ad.y + ae1;
    float a2 = as.z + ad.z + ae2;
    float a3 = as.w + ad.w + ae3;
    a0 = (a0 > 0.f) ? a0 : 0.2f * a0;
    a1 = (a1 > 0.f) ? a1 : 0.2f * a1;
    a2 = (a2 > 0.f) ? a2 : 0.2f * a2;
    a3 = (a3 > 0.f) ? a3 : 0.2f * a3;
    float4 ex;
    ex.x = __expf(fminf(a0, 60.f));
    ex.y = __expf(fminf(a1, 60.f));
    ex.z = __expf(fminf(a2, 60.f));
    ex.w = __expf(fminf(a3, 60.f));
    ((float4*)exs)[e] = ex;
}

// ---------------------------------------------------------------------------
// Single-pass aggregation: one wave per node, quarter-wave per edge.
// csr[j] = (src, eid) read coalesced; exs[eid] is a random 16 B read broadcast
// across the quarter-wave (L2/L3-absorbed); xpb row gather as before.
// ---------------------------------------------------------------------------
__launch_bounds__(256)
__global__ void node_kernel(const float* __restrict__ exs, const int* __restrict__ rowp,
                            const int2* __restrict__ csr, const unsigned* __restrict__ xpb,
                            float* __restrict__ out) {
    int gw = (blockIdx.x * blockDim.x + threadIdx.x) >> 6;
    int lane = threadIdx.x & 63;
    if (gw >= N_NODES) return;
    int sub = lane >> 4;   // edge slot 0..3
    int sl  = lane & 15;   // channel octet
    int h   = sl >> 2;     // head
    int beg = rowp[gw], end = rowp[gw + 1];
    const float4* exs4 = (const float4*)exs;
    const uint4* xp4 = (const uint4*)xpb;   // 16 uint4 per 128-ch row

    float a[8];
#pragma unroll
    for (int c = 0; c < 8; c++) a[c] = 0.f;
    float den = 0.f;

    int j = beg + sub;
    for (; j + 4 < end; j += 8) {
        int2 se0 = csr[j];
        int2 se1 = csr[j + 4];
        float4 e0 = exs4[se0.y];
        float4 e1 = exs4[se1.y];
        uint4 v0 = xp4[(size_t)se0.x * 16 + sl];
        uint4 v1 = xp4[(size_t)se1.x * 16 + sl];
        float ex0 = (h == 0) ? e0.x : (h == 1) ? e0.y : (h == 2) ? e0.z : e0.w;
        float ex1 = (h == 0) ? e1.x : (h == 1) ? e1.y : (h == 2) ? e1.z : e1.w;
        a[0] += ex0 * __uint_as_float(v0.x << 16);
        a[1] += ex0 * __uint_as_float(v0.x & 0xFFFF0000u);
        a[2] += ex0 * __uint_as_float(v0.y << 16);
        a[3] += ex0 * __uint_as_float(v0.y & 0xFFFF0000u);
        a[4] += ex0 * __uint_as_float(v0.z << 16);
        a[5] += ex0 * __uint_as_float(v0.z & 0xFFFF0000u);
        a[6] += ex0 * __uint_as_float(v0.w << 16);
        a[7] += ex0 * __uint_as_float(v0.w & 0xFFFF0000u);
        a[0] += ex1 * __uint_as_float(v1.x << 16);
        a[1] += ex1 * __uint_as_float(v1.x & 0xFFFF0000u);
        a[2] += ex1 * __uint_as_float(v1.y << 16);
        a[3] += ex1 * __uint_as_float(v1.y & 0xFFFF0000u);
        a[4] += ex1 * __uint_as_float(v1.z << 16);
        a[5] += ex1 * __uint_as_float(v1.z & 0xFFFF0000u);
        a[6] += ex1 * __uint_as_float(v1.w << 16);
        a[7] += ex1 * __uint_as_float(v1.w & 0xFFFF0000u);
        den += ex0 + ex1;
    }
    if (j < end) {
        int2 se0 = csr[j];
        float4 e0 = exs4[se0.y];
        uint4 v0 = xp4[(size_t)se0.x * 16 + sl];
        float ex0 = (h == 0) ? e0.x : (h == 1) ? e0.y : (h == 2) ? e0.z : e0.w;
        a[0] += ex0 * __uint_as_float(v0.x << 16);
        a[1] += ex0 * __uint_as_float(v0.x & 0xFFFF0000u);
        a[2] += ex0 * __uint_as_float(v0.y << 16);
        a[3] += ex0 * __uint_as_float(v0.y & 0xFFFF0000u);
        a[4] += ex0 * __uint_as_float(v0.z << 16);
        a[5] += ex0 * __uint_as_float(v0.z & 0xFFFF0000u);
        a[6] += ex0 * __uint_as_float(v0.w << 16);
        a[7] += ex0 * __uint_as_float(v0.w & 0xFFFF0000u);
        den += ex0;
    }
    // reduce over the 4 quarter-waves
#pragma unroll
    for (int c = 0; c < 8; c++) {
        a[c] += __shfl_xor(a[c], 16);
        a[c] += __shfl_xor(a[c], 32);
    }
    den += __shfl_xor(den, 16);
    den += __shfl_xor(den, 32);
    float inv = 1.0f / den;   // deg >= 1 (self loop)
    if (sub == 0) {
        float* op = out + (size_t)gw * 128 + sl * 8;
        ((float4*)op)[0] = make_float4(a[0] * inv, a[1] * inv, a[2] * inv, a[3] * inv);
        ((float4*)op)[1] = make_float4(a[4] * inv, a[5] * inv, a[6] * inv, a[7] * inv);
    }
}

// ---------------------------------------------------------------------------
// BatchNorm statistics + fused update (BN finalize in-block, relu, residual,
// bf16 repack of h for the next layer's MFMA GEMM)
// ---------------------------------------------------------------------------
__launch_bounds__(256)
__global__ void bnstats_kernel(const float* __restrict__ h, float* __restrict__ bnsum,
                               float* __restrict__ bnsum2) {
    __shared__ float ls[256], ls2[256];
    int t = threadIdx.x;
    int c = t & 127, half = t >> 7;
    int r0 = blockIdx.x * 128;
    float s = 0.f, s2 = 0.f;
    int rend = min(r0 + 128, N_NODES);
    for (int r = r0 + half; r < rend; r += 2) {
        float v = h[(size_t)r * 128 + c];
        s += v; s2 += v * v;
    }
    ls[t] = s; ls2[t] = s2;
    __syncthreads();
    if (half == 0) {
        s += ls[t + 128]; s2 += ls2[t + 128];
        atomicAdd(&bnsum[c], s);
        atomicAdd(&bnsum2[c], s2);
    }
}

__launch_bounds__(256)
__global__ void update_kernel(const float* __restrict__ outb, const float* __restrict__ bnsum,
                              const float* __restrict__ bnsum2, const float* __restrict__ gamma,
                              const float* __restrict__ beta, const float* __restrict__ hA,
                              float* __restrict__ dst, unsigned* __restrict__ dstb,
                              int add_res) {
    __shared__ float sc_s[128], sh_s[128];
    int t = threadIdx.x;
    if (t < 128) {
        float mu = bnsum[t] / (float)N_NODES;
        float var = bnsum2[t] / (float)N_NODES - mu * mu;
        float inv = rsqrtf(var + BN_EPS);
        float g = gamma[t] * inv;
        sc_s[t] = g;
        sh_s[t] = beta[t] - mu * g;
    }
    __syncthreads();
    int i = blockIdx.x * blockDim.x + t;
    if (i >= N_NODES * 32) return;
    int c4 = (i & 31) * 4;
    float4 o = ((const float4*)outb)[i];
    float4 v;
    v.x = fmaxf(o.x * sc_s[c4 + 0] + sh_s[c4 + 0], 0.f);
    v.y = fmaxf(o.y * sc_s[c4 + 1] + sh_s[c4 + 1], 0.f);
    v.z = fmaxf(o.z * sc_s[c4 + 2] + sh_s[c4 + 2], 0.f);
    v.w = fmaxf(o.w * sc_s[c4 + 3] + sh_s[c4 + 3], 0.f);
    if (add_res) {
        float4 hh = ((const float4*)hA)[i];
        v.x += hh.x; v.y += hh.y; v.z += hh.z; v.w += hh.w;
    }
    ((float4*)dst)[i] = v;
    ((uint2*)dstb)[i] = make_uint2(bf16pair(v.x, v.y), bf16pair(v.z, v.w));
}

// ---------------------------------------------------------------------------
extern "C" void kernel_launch(void* const* d_in, const int* in_sizes, int n_in,
                              void* d_out, int out_size, void* d_ws, size_t ws_size,
                              hipStream_t stream) {
    const float* x          = (const float*)d_in[0];
    const int*   edge_index = (const int*)d_in[1];
    const float* edge_attr  = (const float*)d_in[2];
    const float* Wp         = (const float*)d_in[3];
    const float* bp         = (const float*)d_in[4];
    const float* W          = (const float*)d_in[5];
    const float* We         = (const float*)d_in[6];
    const float* att_src    = (const float*)d_in[7];
    const float* att_dst    = (const float*)d_in[8];
    const float* att_edge   = (const float*)d_in[9];
    // d_in[10] bias: absorbed exactly by training-mode BN -> skipped
    const float* gamma      = (const float*)d_in[11];
    const float* beta       = (const float*)d_in[12];
    float* outp = (float*)d_out;

    const int* ei_src = edge_index;
    const int* ei_dst = edge_index + N_EDGES;

    char* p = (char*)d_ws;
    auto alloc = [&](size_t nbytes) {
        char* r = p;
        p += (nbytes + 255) & ~(size_t)255;
        return r;
    };
    // zero-initialized region: hist | bcnt | easum | bnsum(4 layers x 256)
    int*   hist     = (int*)alloc((size_t)N_NODES * 4);
    int*   bcnt     = (int*)alloc(256 * 4);
    float* easum    = (float*)alloc(16 * 4);
    float* bnsumall = (float*)alloc((size_t)LAYERS * 256 * 4);
    size_t zero_bytes = (char*)(bnsumall + LAYERS * 256) - (char*)hist;

    float* hA       = (float*)alloc((size_t)N_NODES * 128 * 4);
    unsigned* hAb   = (unsigned*)alloc((size_t)N_NODES * 64 * 4);   // bf16x2, GEMM A feed
    unsigned* xpb   = (unsigned*)alloc((size_t)N_NODES * 64 * 4);   // bf16x2, gather payload
    float* outb     = (float*)alloc((size_t)N_NODES * 128 * 4);
    float* exs      = (float*)alloc((size_t)N_ETOT * 4 * 4);
    float* asrc     = (float*)alloc((size_t)N_NODES * 4 * 4);
    float* adst     = (float*)alloc((size_t)N_NODES * 4 * 4);
    float* wea_all  = (float*)alloc((LAYERS * 48 + 16) * 4);
    float* aloop    = wea_all + LAYERS * 48;
    unsigned short* wb = (unsigned short*)alloc((size_t)LAYERS * 16384 * 2);
    int* rowp       = (int*)alloc(((size_t)N_NODES + 1) * 4);
    int* cursor     = (int*)alloc((size_t)N_NODES * 4);
    unsigned long long* bpk = (unsigned long long*)alloc((size_t)N_ETOT * 8);
    int2* csr       = (int2*)alloc((size_t)N_ETOT * 8);
    int* bsum       = (int*)alloc(256 * 4);
    int* boff       = (int*)alloc(256 * 4);
    int* bbase      = (int*)alloc(256 * 4);
    int* bcursor    = (int*)alloc(256 * 4);

    const int EB = (N_ETOT + 255) / 256;

    (void)hipMemsetAsync(hist, 0, zero_bytes, stream);

    // ---- CSR build, bucketed (graph fixed across layers) ----
    hist2_kernel<<<EB, 256, 0, stream>>>(ei_dst, hist, bcnt);
    blocksum_kernel<<<SCAN_BLK, 256, 0, stream>>>(hist, bsum);
    bscan_kernel<<<1, 256, 0, stream>>>(bsum, boff, rowp);
    rowp_kernel<<<SCAN_BLK, 256, 0, stream>>>(hist, boff, rowp, cursor);
    bscan2_kernel<<<1, 256, 0, stream>>>(bcnt, bbase, bcursor);
    bfill_kernel<<<EB, 256, 0, stream>>>(ei_src, ei_dst, bcursor, bpk);
    cscatter_kernel<<<EB, 256, 0, stream>>>(bpk, cursor, csr);

    // ---- edge-attr mean + folded matrices + W pre-pack (all layers) ----
    eamean_kernel<<<256, 256, 0, stream>>>(edge_attr, easum);
    prep_kernel<<<1, 256, 0, stream>>>(easum, We, att_edge, wea_all, aloop);
    packW_kernel<<<(LAYERS * HID * HID + 255) / 256, 256, 0, stream>>>(W, wb);

    // ---- initial projection (f32 SIMD, bias+relu, dual f32/bf16 store) ----
    gemm0_kernel<<<(N_NODES + 63) / 64, 256, 0, stream>>>(x, Wp, bp, hA, hAb);

    for (int l = 0; l < LAYERS; l++) {
        float* bnsum  = bnsumall + l * 256;
        float* bnsum2 = bnsum + 128;
        gemm_mfma_kernel<<<(N_NODES + 63) / 64, 256, 0, stream>>>(
            (const unsigned short*)hAb, wb + (size_t)l * 16384,
            att_src + l * 128, att_dst + l * 128, xpb, asrc, adst);
        edge_kernel<<<EB, 256, 0, stream>>>(ei_src, ei_dst, edge_attr, asrc, adst,
                                            wea_all + l * 48, aloop + l * 4, exs);
        node_kernel<<<(N_NODES + 3) / 4, 256, 0, stream>>>(exs, rowp, csr, xpb, outb);
        bnstats_kernel<<<(N_NODES + 127) / 128, 256, 0, stream>>>(outb, bnsum, bnsum2);
        float* dst = (l == LAYERS - 1) ? outp : hA;
        update_kernel<<<(N_NODES * 32 + 255) / 256, 256, 0, stream>>>(
            outb, bnsum, bnsum2, gamma + l * 128, beta + l * 128, hA, dst, hAb,
            (l > 0) ? 1 : 0);
    }
}

// Round 9
// 749.419 us; speedup vs baseline: 1.7329x; 1.7329x over previous
//
#include <hip/hip_runtime.h>

// Problem constants (match reference setup_inputs)
constexpr int N_NODES = 50000;
constexpr int N_EDGES = 800000;
constexpr int N_ETOT  = N_EDGES + N_NODES;   // with self loops
constexpr int HID     = 128;
constexpr int HEADS   = 4;
constexpr int ED      = 12;
constexpr int LAYERS  = 4;
constexpr float BN_EPS = 1e-5f;
constexpr int SCAN_BLK = (N_NODES + 255) / 256;   // 196

typedef __attribute__((ext_vector_type(8))) short short8;
typedef __attribute__((ext_vector_type(4))) float floatx4;

__device__ inline unsigned bf16pair(float a, float b) {
    unsigned ua = __float_as_uint(a), ub = __float_as_uint(b);
    ua = (ua + 0x7FFFu + ((ua >> 16) & 1u)) >> 16;
    ub = (ub + 0x7FFFu + ((ub >> 16) & 1u)) >> 16;
    return ua | (ub << 16);
}

// ---------------------------------------------------------------------------
// CSR build: histogram of dst, multi-block scan, direct scatter of int2
// (src,eid) with per-node cursors (50k addresses -> low atomic contention;
// R8's 196-bucket variant serialized at 526 us — do NOT re-concentrate).
// ---------------------------------------------------------------------------
__global__ void hist_kernel(const int* __restrict__ dst, int* __restrict__ hist) {
    int e = blockIdx.x * blockDim.x + threadIdx.x;
    if (e >= N_ETOT) return;
    int d = (e < N_EDGES) ? dst[e] : (e - N_EDGES);
    atomicAdd(&hist[d], 1);
}

__global__ void blocksum_kernel(const int* __restrict__ hist, int* __restrict__ bsum) {
    __shared__ int sd[256];
    int t = threadIdx.x;
    int n = blockIdx.x * 256 + t;
    sd[t] = (n < N_NODES) ? hist[n] : 0;
    __syncthreads();
#pragma unroll
    for (int off = 128; off; off >>= 1) {
        if (t < off) sd[t] += sd[t + off];
        __syncthreads();
    }
    if (t == 0) bsum[blockIdx.x] = sd[0];
}

__global__ void bscan_kernel(const int* __restrict__ bsum, int* __restrict__ boff,
                             int* __restrict__ rowp) {
    __shared__ int sd[256];
    int t = threadIdx.x;
    int v = (t < SCAN_BLK) ? bsum[t] : 0;
    sd[t] = v;
    __syncthreads();
#pragma unroll
    for (int off = 1; off < 256; off <<= 1) {
        int u = (t >= off) ? sd[t - off] : 0;
        __syncthreads();
        sd[t] += u;
        __syncthreads();
    }
    if (t < SCAN_BLK) boff[t] = sd[t] - v;
    if (t == 255) rowp[N_NODES] = sd[255];
}

__global__ void rowp_kernel(const int* __restrict__ hist, const int* __restrict__ boff,
                            int* __restrict__ rowp, int* __restrict__ cursor) {
    __shared__ int sd[256];
    int t = threadIdx.x;
    int n = blockIdx.x * 256 + t;
    int v = (n < N_NODES) ? hist[n] : 0;
    sd[t] = v;
    __syncthreads();
#pragma unroll
    for (int off = 1; off < 256; off <<= 1) {
        int u = (t >= off) ? sd[t - off] : 0;
        __syncthreads();
        sd[t] += u;
        __syncthreads();
    }
    if (n < N_NODES) {
        int excl = sd[t] - v + boff[blockIdx.x];
        rowp[n] = excl;
        cursor[n] = excl;
    }
}

__global__ void scatter_kernel(const int* __restrict__ src, const int* __restrict__ dst,
                               int* __restrict__ cursor, int2* __restrict__ csr) {
    int e = blockIdx.x * blockDim.x + threadIdx.x;
    if (e >= N_ETOT) return;
    int s, d;
    if (e < N_EDGES) { s = src[e]; d = dst[e]; }
    else             { s = d = e - N_EDGES; }
    int pos = atomicAdd(&cursor[d], 1);
    csr[pos] = make_int2(s, e);
}

// ---------------------------------------------------------------------------
// edge_attr mean (over real edges) -> easum[12]
// ---------------------------------------------------------------------------
__launch_bounds__(256)
__global__ void eamean_kernel(const float* __restrict__ ea, float* __restrict__ easum) {
    __shared__ float ls[12];
    int t = threadIdx.x;
    if (t < 12) ls[t] = 0.f;
    __syncthreads();
    float loc[12];
#pragma unroll
    for (int d = 0; d < 12; d++) loc[d] = 0.f;
    int stride = gridDim.x * 256;
    for (int e = blockIdx.x * 256 + t; e < N_EDGES; e += stride) {
        const float* er = ea + (size_t)e * ED;
#pragma unroll
        for (int d = 0; d < 12; d++) loc[d] += er[d];
    }
#pragma unroll
    for (int d = 0; d < 12; d++) atomicAdd(&ls[d], loc[d]);
    __syncthreads();
    if (t < 12) atomicAdd(&easum[t], ls[t]);
}

__global__ void prep_kernel(const float* __restrict__ easum, const float* __restrict__ We,
                            const float* __restrict__ att_edge, float* __restrict__ wea_all,
                            float* __restrict__ aloop) {
    __shared__ float em[12];
    __shared__ float weash[LAYERS * ED * HEADS];
    int t = threadIdx.x;
    if (t < 12) em[t] = easum[t] / (float)N_EDGES;
    if (t < LAYERS * ED * HEADS) {
        int l = t / (ED * HEADS);
        int r = t % (ED * HEADS);
        int d = r / HEADS;
        int h = r % HEADS;
        float sum = 0.f;
#pragma unroll
        for (int c = 0; c < 32; c++)
            sum += We[((size_t)(l * ED + d)) * HID + h * 32 + c] *
                   att_edge[(l * HEADS + h) * 32 + c];
        wea_all[t] = sum;
        weash[t] = sum;
    }
    __syncthreads();
    if (t < LAYERS * HEADS) {
        int l = t / HEADS, h = t % HEADS;
        float s = 0.f;
#pragma unroll
        for (int d = 0; d < 12; d++) s += em[d] * weash[l * ED * HEADS + d * HEADS + h];
        aloop[t] = s;
    }
}

// ---------------------------------------------------------------------------
// Pack all layer weights W[l][k][n] (f32) into per-lane MFMA B-fragment order.
// ---------------------------------------------------------------------------
__global__ void packW_kernel(const float* __restrict__ W, unsigned short* __restrict__ wb) {
    int idx = blockIdx.x * 256 + threadIdx.x;
    if (idx >= LAYERS * HID * HID) return;
    int l = idx >> 14;
    int k = (idx >> 7) & 127;
    int n = idx & 127;
    unsigned u = __float_as_uint(W[idx]);
    u = (u + 0x7FFFu + ((u >> 16) & 1u)) >> 16;
    int kt = k >> 5, q = (k & 31) >> 3, j = k & 7;
    int nt = n >> 4, c = n & 15;
    int lane = q * 16 + c;
    wb[(size_t)l * 16384 + ((size_t)(kt * 8 + nt) * 64 + lane) * 8 + j] = (unsigned short)u;
}

// ---------------------------------------------------------------------------
// Initial projection GEMM (f32 SIMD): h = relu(x @ Wp + bp); dual f32/bf16 out.
// ---------------------------------------------------------------------------
__launch_bounds__(256)
__global__ void gemm0_kernel(const float* __restrict__ A, const float* __restrict__ B,
                             const float* __restrict__ bias, float* __restrict__ C,
                             unsigned* __restrict__ Cb) {
    constexpr int K = 64;
    __shared__ float Bs[K * 128];
    int t = threadIdx.x;
    const float4* B4 = (const float4*)B;
    float4* Bs4 = (float4*)Bs;
#pragma unroll
    for (int i = t; i < K * 32; i += 256) Bs4[i] = B4[i];
    __syncthreads();

    int c0 = (t & 15) * 8;
    int r0 = (t >> 4) * 4;
    int rbase = blockIdx.x * 64 + r0;

    float acc[4][8];
#pragma unroll
    for (int j = 0; j < 4; j++)
#pragma unroll
        for (int c = 0; c < 8; c++) acc[j][c] = 0.f;

    const float4* A4 = (const float4*)A;
    int rg[4];
#pragma unroll
    for (int j = 0; j < 4; j++) rg[j] = min(rbase + j, N_NODES - 1);

    for (int kk = 0; kk < K; kk += 4) {
        float4 av[4];
#pragma unroll
        for (int j = 0; j < 4; j++) av[j] = A4[(size_t)rg[j] * (K / 4) + (kk >> 2)];
        float a_arr[4][4];
#pragma unroll
        for (int j = 0; j < 4; j++) {
            a_arr[j][0] = av[j].x; a_arr[j][1] = av[j].y;
            a_arr[j][2] = av[j].z; a_arr[j][3] = av[j].w;
        }
#pragma unroll
        for (int jj = 0; jj < 4; jj++) {
            float4 b0 = Bs4[(kk + jj) * 32 + (c0 >> 2)];
            float4 b1 = Bs4[(kk + jj) * 32 + (c0 >> 2) + 1];
#pragma unroll
            for (int j = 0; j < 4; j++) {
                float a = a_arr[j][jj];
                acc[j][0] += a * b0.x; acc[j][1] += a * b0.y;
                acc[j][2] += a * b0.z; acc[j][3] += a * b0.w;
                acc[j][4] += a * b1.x; acc[j][5] += a * b1.y;
                acc[j][6] += a * b1.z; acc[j][7] += a * b1.w;
            }
        }
    }

#pragma unroll
    for (int j = 0; j < 4; j++) {
        int r = rbase + j;
        if (r < N_NODES) {
            float o[8];
#pragma unroll
            for (int c = 0; c < 8; c++) o[c] = fmaxf(acc[j][c] + bias[c0 + c], 0.f);
            ((float4*)(C + (size_t)r * 128 + c0))[0] = make_float4(o[0], o[1], o[2], o[3]);
            ((float4*)(C + (size_t)r * 128 + c0 + 4))[0] = make_float4(o[4], o[5], o[6], o[7]);
            uint4 pk;
            pk.x = bf16pair(o[0], o[1]); pk.y = bf16pair(o[2], o[3]);
            pk.z = bf16pair(o[4], o[5]); pk.w = bf16pair(o[6], o[7]);
            ((uint4*)(Cb + (size_t)r * 64 + (c0 >> 1)))[0] = pk;
        }
    }
}

// ---------------------------------------------------------------------------
// Layer projection GEMM via MFMA bf16 + fused attention dots (see R5 notes).
// ---------------------------------------------------------------------------
__launch_bounds__(256)
__global__ void gemm_mfma_kernel(const unsigned short* __restrict__ hAb,
                                 const unsigned short* __restrict__ wb,
                                 const float* __restrict__ att_s,
                                 const float* __restrict__ att_d,
                                 unsigned* __restrict__ xpb,
                                 float* __restrict__ asrc, float* __restrict__ adst) {
    __shared__ float lds[4][16][129];
    int t = threadIdx.x;
    int w = t >> 6, lane = t & 63;
    int rbase = blockIdx.x * 64 + w * 16;
    int mrow = lane & 15, quad = lane >> 4;

    floatx4 acc[8];
#pragma unroll
    for (int nt = 0; nt < 8; nt++) acc[nt] = (floatx4){0.f, 0.f, 0.f, 0.f};

    int arow = min(rbase + mrow, N_NODES - 1);
    const short8* wb8 = (const short8*)wb;
#pragma unroll
    for (int kt = 0; kt < 4; kt++) {
        short8 afrag = *(const short8*)(hAb + (size_t)arow * 128 + kt * 32 + quad * 8);
#pragma unroll
        for (int nt = 0; nt < 8; nt++) {
            short8 bfrag = wb8[(kt * 8 + nt) * 64 + lane];
            acc[nt] = __builtin_amdgcn_mfma_f32_16x16x32_bf16(afrag, bfrag, acc[nt], 0, 0, 0);
        }
    }

    // C layout -> LDS (per-wave region; same-wave read below, no barrier)
#pragma unroll
    for (int nt = 0; nt < 8; nt++)
#pragma unroll
        for (int rr = 0; rr < 4; rr++)
            lds[w][quad * 4 + rr][nt * 16 + mrow] = acc[nt][rr];

    int row = lane >> 2, h = lane & 3;
    int r = rbase + row;
    float vals[32];
    float ps = 0.f, pd = 0.f;
#pragma unroll
    for (int c = 0; c < 32; c++) {
        float v = lds[w][row][h * 32 + c];
        vals[c] = v;
        ps += v * att_s[h * 32 + c];
        pd += v * att_d[h * 32 + c];
    }
    if (r < N_NODES) {
        unsigned* dstp = xpb + (size_t)r * 64 + h * 16;
#pragma unroll
        for (int qq = 0; qq < 4; qq++) {
            uint4 o;
            o.x = bf16pair(vals[qq * 8 + 0], vals[qq * 8 + 1]);
            o.y = bf16pair(vals[qq * 8 + 2], vals[qq * 8 + 3]);
            o.z = bf16pair(vals[qq * 8 + 4], vals[qq * 8 + 5]);
            o.w = bf16pair(vals[qq * 8 + 6], vals[qq * 8 + 7]);
            ((uint4*)dstp)[qq] = o;
        }
        asrc[r * 4 + h] = ps;
        adst[r * 4 + h] = pd;
    }
}

// ---------------------------------------------------------------------------
// Per-edge: ex = exp(leakyrelu(a_src+a_dst+a_edge)), stored COALESCED at [e].
// ---------------------------------------------------------------------------
__launch_bounds__(256)
__global__ void edge_kernel(const int* __restrict__ src, const int* __restrict__ dst,
                            const float* __restrict__ ea, const float* __restrict__ asrc,
                            const float* __restrict__ adst, const float* __restrict__ wea,
                            const float* __restrict__ aloop, float* __restrict__ exs) {
    int e = blockIdx.x * blockDim.x + threadIdx.x;
    if (e >= N_ETOT) return;
    int s, d;
    float ae0, ae1, ae2, ae3;
    if (e < N_EDGES) {
        s = src[e]; d = dst[e];
        ae0 = ae1 = ae2 = ae3 = 0.f;
        const float* er = ea + (size_t)e * ED;
#pragma unroll
        for (int dd = 0; dd < 12; dd++) {
            float v = er[dd];
            ae0 += v * wea[dd * 4 + 0];
            ae1 += v * wea[dd * 4 + 1];
            ae2 += v * wea[dd * 4 + 2];
            ae3 += v * wea[dd * 4 + 3];
        }
    } else {
        s = d = e - N_EDGES;
        ae0 = aloop[0]; ae1 = aloop[1]; ae2 = aloop[2]; ae3 = aloop[3];
    }
    float4 as = ((const float4*)asrc)[s];
    float4 ad = ((const float4*)adst)[d];
    float a0 = as.x + ad.x + ae0;
    float a1 = as.y + ad.y + ae1;
    float a2 = as.z + ad.z + ae2;
    float a3 = as.w + ad.w + ae3;
    a0 = (a0 > 0.f) ? a0 : 0.2f * a0;
    a1 = (a1 > 0.f) ? a1 : 0.2f * a1;
    a2 = (a2 > 0.f) ? a2 : 0.2f * a2;
    a3 = (a3 > 0.f) ? a3 : 0.2f * a3;
    float4 ex;
    ex.x = __expf(fminf(a0, 60.f));
    ex.y = __expf(fminf(a1, 60.f));
    ex.z = __expf(fminf(a2, 60.f));
    ex.w = __expf(fminf(a3, 60.f));
    ((float4*)exs)[e] = ex;
}

// ---------------------------------------------------------------------------
// Single-pass aggregation: one wave per node, quarter-wave per edge.
// csr[j] = (src, eid) read coalesced; exs[eid] is a random 16 B read broadcast
// across the quarter-wave (L2/L3-absorbed); xpb row gather as before.
// ---------------------------------------------------------------------------
__launch_bounds__(256)
__global__ void node_kernel(const float* __restrict__ exs, const int* __restrict__ rowp,
                            const int2* __restrict__ csr, const unsigned* __restrict__ xpb,
                            float* __restrict__ out) {
    int gw = (blockIdx.x * blockDim.x + threadIdx.x) >> 6;
    int lane = threadIdx.x & 63;
    if (gw >= N_NODES) return;
    int sub = lane >> 4;   // edge slot 0..3
    int sl  = lane & 15;   // channel octet
    int h   = sl >> 2;     // head
    int beg = rowp[gw], end = rowp[gw + 1];
    const float4* exs4 = (const float4*)exs;
    const uint4* xp4 = (const uint4*)xpb;   // 16 uint4 per 128-ch row

    float a[8];
#pragma unroll
    for (int c = 0; c < 8; c++) a[c] = 0.f;
    float den = 0.f;

    int j = beg + sub;
    for (; j + 4 < end; j += 8) {
        int2 se0 = csr[j];
        int2 se1 = csr[j + 4];
        float4 e0 = exs4[se0.y];
        float4 e1 = exs4[se1.y];
        uint4 v0 = xp4[(size_t)se0.x * 16 + sl];
        uint4 v1 = xp4[(size_t)se1.x * 16 + sl];
        float ex0 = (h == 0) ? e0.x : (h == 1) ? e0.y : (h == 2) ? e0.z : e0.w;
        float ex1 = (h == 0) ? e1.x : (h == 1) ? e1.y : (h == 2) ? e1.z : e1.w;
        a[0] += ex0 * __uint_as_float(v0.x << 16);
        a[1] += ex0 * __uint_as_float(v0.x & 0xFFFF0000u);
        a[2] += ex0 * __uint_as_float(v0.y << 16);
        a[3] += ex0 * __uint_as_float(v0.y & 0xFFFF0000u);
        a[4] += ex0 * __uint_as_float(v0.z << 16);
        a[5] += ex0 * __uint_as_float(v0.z & 0xFFFF0000u);
        a[6] += ex0 * __uint_as_float(v0.w << 16);
        a[7] += ex0 * __uint_as_float(v0.w & 0xFFFF0000u);
        a[0] += ex1 * __uint_as_float(v1.x << 16);
        a[1] += ex1 * __uint_as_float(v1.x & 0xFFFF0000u);
        a[2] += ex1 * __uint_as_float(v1.y << 16);
        a[3] += ex1 * __uint_as_float(v1.y & 0xFFFF0000u);
        a[4] += ex1 * __uint_as_float(v1.z << 16);
        a[5] += ex1 * __uint_as_float(v1.z & 0xFFFF0000u);
        a[6] += ex1 * __uint_as_float(v1.w << 16);
        a[7] += ex1 * __uint_as_float(v1.w & 0xFFFF0000u);
        den += ex0 + ex1;
    }
    if (j < end) {
        int2 se0 = csr[j];
        float4 e0 = exs4[se0.y];
        uint4 v0 = xp4[(size_t)se0.x * 16 + sl];
        float ex0 = (h == 0) ? e0.x : (h == 1) ? e0.y : (h == 2) ? e0.z : e0.w;
        a[0] += ex0 * __uint_as_float(v0.x << 16);
        a[1] += ex0 * __uint_as_float(v0.x & 0xFFFF0000u);
        a[2] += ex0 * __uint_as_float(v0.y << 16);
        a[3] += ex0 * __uint_as_float(v0.y & 0xFFFF0000u);
        a[4] += ex0 * __uint_as_float(v0.z << 16);
        a[5] += ex0 * __uint_as_float(v0.z & 0xFFFF0000u);
        a[6] += ex0 * __uint_as_float(v0.w << 16);
        a[7] += ex0 * __uint_as_float(v0.w & 0xFFFF0000u);
        den += ex0;
    }
    // reduce over the 4 quarter-waves
#pragma unroll
    for (int c = 0; c < 8; c++) {
        a[c] += __shfl_xor(a[c], 16);
        a[c] += __shfl_xor(a[c], 32);
    }
    den += __shfl_xor(den, 16);
    den += __shfl_xor(den, 32);
    float inv = 1.0f / den;   // deg >= 1 (self loop)
    if (sub == 0) {
        float* op = out + (size_t)gw * 128 + sl * 8;
        ((float4*)op)[0] = make_float4(a[0] * inv, a[1] * inv, a[2] * inv, a[3] * inv);
        ((float4*)op)[1] = make_float4(a[4] * inv, a[5] * inv, a[6] * inv, a[7] * inv);
    }
}

// ---------------------------------------------------------------------------
// BatchNorm statistics + fused update (BN finalize in-block, relu, residual,
// bf16 repack of h for the next layer's MFMA GEMM)
// ---------------------------------------------------------------------------
__launch_bounds__(256)
__global__ void bnstats_kernel(const float* __restrict__ h, float* __restrict__ bnsum,
                               float* __restrict__ bnsum2) {
    __shared__ float ls[256], ls2[256];
    int t = threadIdx.x;
    int c = t & 127, half = t >> 7;
    int r0 = blockIdx.x * 128;
    float s = 0.f, s2 = 0.f;
    int rend = min(r0 + 128, N_NODES);
    for (int r = r0 + half; r < rend; r += 2) {
        float v = h[(size_t)r * 128 + c];
        s += v; s2 += v * v;
    }
    ls[t] = s; ls2[t] = s2;
    __syncthreads();
    if (half == 0) {
        s += ls[t + 128]; s2 += ls2[t + 128];
        atomicAdd(&bnsum[c], s);
        atomicAdd(&bnsum2[c], s2);
    }
}

__launch_bounds__(256)
__global__ void update_kernel(const float* __restrict__ outb, const float* __restrict__ bnsum,
                              const float* __restrict__ bnsum2, const float* __restrict__ gamma,
                              const float* __restrict__ beta, const float* __restrict__ hA,
                              float* __restrict__ dst, unsigned* __restrict__ dstb,
                              int add_res) {
    __shared__ float sc_s[128], sh_s[128];
    int t = threadIdx.x;
    if (t < 128) {
        float mu = bnsum[t] / (float)N_NODES;
        float var = bnsum2[t] / (float)N_NODES - mu * mu;
        float inv = rsqrtf(var + BN_EPS);
        float g = gamma[t] * inv;
        sc_s[t] = g;
        sh_s[t] = beta[t] - mu * g;
    }
    __syncthreads();
    int i = blockIdx.x * blockDim.x + t;
    if (i >= N_NODES * 32) return;
    int c4 = (i & 31) * 4;
    float4 o = ((const float4*)outb)[i];
    float4 v;
    v.x = fmaxf(o.x * sc_s[c4 + 0] + sh_s[c4 + 0], 0.f);
    v.y = fmaxf(o.y * sc_s[c4 + 1] + sh_s[c4 + 1], 0.f);
    v.z = fmaxf(o.z * sc_s[c4 + 2] + sh_s[c4 + 2], 0.f);
    v.w = fmaxf(o.w * sc_s[c4 + 3] + sh_s[c4 + 3], 0.f);
    if (add_res) {
        float4 hh = ((const float4*)hA)[i];
        v.x += hh.x; v.y += hh.y; v.z += hh.z; v.w += hh.w;
    }
    ((float4*)dst)[i] = v;
    ((uint2*)dstb)[i] = make_uint2(bf16pair(v.x, v.y), bf16pair(v.z, v.w));
}

// ---------------------------------------------------------------------------
extern "C" void kernel_launch(void* const* d_in, const int* in_sizes, int n_in,
                              void* d_out, int out_size, void* d_ws, size_t ws_size,
                              hipStream_t stream) {
    const float* x          = (const float*)d_in[0];
    const int*   edge_index = (const int*)d_in[1];
    const float* edge_attr  = (const float*)d_in[2];
    const float* Wp         = (const float*)d_in[3];
    const float* bp         = (const float*)d_in[4];
    const float* W          = (const float*)d_in[5];
    const float* We         = (const float*)d_in[6];
    const float* att_src    = (const float*)d_in[7];
    const float* att_dst    = (const float*)d_in[8];
    const float* att_edge   = (const float*)d_in[9];
    // d_in[10] bias: absorbed exactly by training-mode BN -> skipped
    const float* gamma      = (const float*)d_in[11];
    const float* beta       = (const float*)d_in[12];
    float* outp = (float*)d_out;

    const int* ei_src = edge_index;
    const int* ei_dst = edge_index + N_EDGES;

    char* p = (char*)d_ws;
    auto alloc = [&](size_t nbytes) {
        char* r = p;
        p += (nbytes + 255) & ~(size_t)255;
        return r;
    };
    // zero-initialized region: hist | easum | bnsum(4 layers x 256)
    int*   hist     = (int*)alloc((size_t)N_NODES * 4);
    float* easum    = (float*)alloc(16 * 4);
    float* bnsumall = (float*)alloc((size_t)LAYERS * 256 * 4);
    size_t zero_bytes = (char*)(bnsumall + LAYERS * 256) - (char*)hist;

    float* hA       = (float*)alloc((size_t)N_NODES * 128 * 4);
    unsigned* hAb   = (unsigned*)alloc((size_t)N_NODES * 64 * 4);   // bf16x2, GEMM A feed
    unsigned* xpb   = (unsigned*)alloc((size_t)N_NODES * 64 * 4);   // bf16x2, gather payload
    float* outb     = (float*)alloc((size_t)N_NODES * 128 * 4);
    float* exs      = (float*)alloc((size_t)N_ETOT * 4 * 4);
    float* asrc     = (float*)alloc((size_t)N_NODES * 4 * 4);
    float* adst     = (float*)alloc((size_t)N_NODES * 4 * 4);
    float* wea_all  = (float*)alloc((LAYERS * 48 + 16) * 4);
    float* aloop    = wea_all + LAYERS * 48;
    unsigned short* wb = (unsigned short*)alloc((size_t)LAYERS * 16384 * 2);
    int* rowp       = (int*)alloc(((size_t)N_NODES + 1) * 4);
    int* cursor     = (int*)alloc((size_t)N_NODES * 4);
    int2* csr       = (int2*)alloc((size_t)N_ETOT * 8);
    int* bsum       = (int*)alloc(256 * 4);
    int* boff       = (int*)alloc(256 * 4);

    const int EB = (N_ETOT + 255) / 256;

    (void)hipMemsetAsync(hist, 0, zero_bytes, stream);

    // ---- CSR build (graph fixed across layers) ----
    hist_kernel<<<EB, 256, 0, stream>>>(ei_dst, hist);
    blocksum_kernel<<<SCAN_BLK, 256, 0, stream>>>(hist, bsum);
    bscan_kernel<<<1, 256, 0, stream>>>(bsum, boff, rowp);
    rowp_kernel<<<SCAN_BLK, 256, 0, stream>>>(hist, boff, rowp, cursor);
    scatter_kernel<<<EB, 256, 0, stream>>>(ei_src, ei_dst, cursor, csr);

    // ---- edge-attr mean + folded matrices + W pre-pack (all layers) ----
    eamean_kernel<<<256, 256, 0, stream>>>(edge_attr, easum);
    prep_kernel<<<1, 256, 0, stream>>>(easum, We, att_edge, wea_all, aloop);
    packW_kernel<<<(LAYERS * HID * HID + 255) / 256, 256, 0, stream>>>(W, wb);

    // ---- initial projection (f32 SIMD, bias+relu, dual f32/bf16 store) ----
    gemm0_kernel<<<(N_NODES + 63) / 64, 256, 0, stream>>>(x, Wp, bp, hA, hAb);

    for (int l = 0; l < LAYERS; l++) {
        float* bnsum  = bnsumall + l * 256;
        float* bnsum2 = bnsum + 128;
        gemm_mfma_kernel<<<(N_NODES + 63) / 64, 256, 0, stream>>>(
            (const unsigned short*)hAb, wb + (size_t)l * 16384,
            att_src + l * 128, att_dst + l * 128, xpb, asrc, adst);
        edge_kernel<<<EB, 256, 0, stream>>>(ei_src, ei_dst, edge_attr, asrc, adst,
                                            wea_all + l * 48, aloop + l * 4, exs);
        node_kernel<<<(N_NODES + 3) / 4, 256, 0, stream>>>(exs, rowp, csr, xpb, outb);
        bnstats_kernel<<<(N_NODES + 127) / 128, 256, 0, stream>>>(outb, bnsum, bnsum2);
        float* dst = (l == LAYERS - 1) ? outp : hA;
        update_kernel<<<(N_NODES * 32 + 255) / 256, 256, 0, stream>>>(
            outb, bnsum, bnsum2, gamma + l * 128, beta + l * 128, hA, dst, hAb,
            (l > 0) ? 1 : 0);
    }
}

// Round 10
// 672.846 us; speedup vs baseline: 1.9301x; 1.1138x over previous
//
#include <hip/hip_runtime.h>

// Problem constants (match reference setup_inputs)
constexpr int N_NODES = 50000;
constexpr int N_EDGES = 800000;
constexpr int N_ETOT  = N_EDGES + N_NODES;   // with self loops
constexpr int HID     = 128;
constexpr int HEADS   = 4;
constexpr int ED      = 12;
constexpr int LAYERS  = 4;
constexpr float BN_EPS = 1e-5f;
constexpr int SCAN_BLK = (N_NODES + 255) / 256;   // 196

typedef __attribute__((ext_vector_type(8))) short short8;
typedef __attribute__((ext_vector_type(4))) float floatx4;

__device__ inline unsigned bf16pair(float a, float b) {
    unsigned ua = __float_as_uint(a), ub = __float_as_uint(b);
    ua = (ua + 0x7FFFu + ((ua >> 16) & 1u)) >> 16;
    ub = (ub + 0x7FFFu + ((ub >> 16) & 1u)) >> 16;
    return ua | (ub << 16);
}

// ---------------------------------------------------------------------------
// CSR build: histogram of dst, multi-block scan, direct scatter of int2
// (src,eid) with per-node cursors. NOTE (R8/R9 measured): the random 8 B
// store costs one 64 B line each (54 MB, ~830 GB/s random-write floor, 65us);
// bucketing to fewer cursors serializes atomics (526us). This is the floor.
// ---------------------------------------------------------------------------
__global__ void hist_kernel(const int* __restrict__ dst, int* __restrict__ hist) {
    int e = blockIdx.x * blockDim.x + threadIdx.x;
    if (e >= N_ETOT) return;
    int d = (e < N_EDGES) ? dst[e] : (e - N_EDGES);
    atomicAdd(&hist[d], 1);
}

__global__ void blocksum_kernel(const int* __restrict__ hist, int* __restrict__ bsum) {
    __shared__ int sd[256];
    int t = threadIdx.x;
    int n = blockIdx.x * 256 + t;
    sd[t] = (n < N_NODES) ? hist[n] : 0;
    __syncthreads();
#pragma unroll
    for (int off = 128; off; off >>= 1) {
        if (t < off) sd[t] += sd[t + off];
        __syncthreads();
    }
    if (t == 0) bsum[blockIdx.x] = sd[0];
}

__global__ void bscan_kernel(const int* __restrict__ bsum, int* __restrict__ boff,
                             int* __restrict__ rowp) {
    __shared__ int sd[256];
    int t = threadIdx.x;
    int v = (t < SCAN_BLK) ? bsum[t] : 0;
    sd[t] = v;
    __syncthreads();
#pragma unroll
    for (int off = 1; off < 256; off <<= 1) {
        int u = (t >= off) ? sd[t - off] : 0;
        __syncthreads();
        sd[t] += u;
        __syncthreads();
    }
    if (t < SCAN_BLK) boff[t] = sd[t] - v;
    if (t == 255) rowp[N_NODES] = sd[255];
}

__global__ void rowp_kernel(const int* __restrict__ hist, const int* __restrict__ boff,
                            int* __restrict__ rowp, int* __restrict__ cursor) {
    __shared__ int sd[256];
    int t = threadIdx.x;
    int n = blockIdx.x * 256 + t;
    int v = (n < N_NODES) ? hist[n] : 0;
    sd[t] = v;
    __syncthreads();
#pragma unroll
    for (int off = 1; off < 256; off <<= 1) {
        int u = (t >= off) ? sd[t - off] : 0;
        __syncthreads();
        sd[t] += u;
        __syncthreads();
    }
    if (n < N_NODES) {
        int excl = sd[t] - v + boff[blockIdx.x];
        rowp[n] = excl;
        cursor[n] = excl;
    }
}

__global__ void scatter_kernel(const int* __restrict__ src, const int* __restrict__ dst,
                               int* __restrict__ cursor, int2* __restrict__ csr) {
    int e = blockIdx.x * blockDim.x + threadIdx.x;
    if (e >= N_ETOT) return;
    int s, d;
    if (e < N_EDGES) { s = src[e]; d = dst[e]; }
    else             { s = d = e - N_EDGES; }
    int pos = atomicAdd(&cursor[d], 1);
    csr[pos] = make_int2(s, e);
}

// ---------------------------------------------------------------------------
// edge_attr mean (over real edges) -> easum[12]
// ---------------------------------------------------------------------------
__launch_bounds__(256)
__global__ void eamean_kernel(const float* __restrict__ ea, float* __restrict__ easum) {
    __shared__ float ls[12];
    int t = threadIdx.x;
    if (t < 12) ls[t] = 0.f;
    __syncthreads();
    float loc[12];
#pragma unroll
    for (int d = 0; d < 12; d++) loc[d] = 0.f;
    int stride = gridDim.x * 256;
    for (int e = blockIdx.x * 256 + t; e < N_EDGES; e += stride) {
        const float* er = ea + (size_t)e * ED;
#pragma unroll
        for (int d = 0; d < 12; d++) loc[d] += er[d];
    }
#pragma unroll
    for (int d = 0; d < 12; d++) atomicAdd(&ls[d], loc[d]);
    __syncthreads();
    if (t < 12) atomicAdd(&easum[t], ls[t]);
}

__global__ void prep_kernel(const float* __restrict__ easum, const float* __restrict__ We,
                            const float* __restrict__ att_edge, float* __restrict__ wea_all,
                            float* __restrict__ aloop) {
    __shared__ float em[12];
    __shared__ float weash[LAYERS * ED * HEADS];
    int t = threadIdx.x;
    if (t < 12) em[t] = easum[t] / (float)N_EDGES;
    if (t < LAYERS * ED * HEADS) {
        int l = t / (ED * HEADS);
        int r = t % (ED * HEADS);
        int d = r / HEADS;
        int h = r % HEADS;
        float sum = 0.f;
#pragma unroll
        for (int c = 0; c < 32; c++)
            sum += We[((size_t)(l * ED + d)) * HID + h * 32 + c] *
                   att_edge[(l * HEADS + h) * 32 + c];
        wea_all[t] = sum;
        weash[t] = sum;
    }
    __syncthreads();
    if (t < LAYERS * HEADS) {
        int l = t / HEADS, h = t % HEADS;
        float s = 0.f;
#pragma unroll
        for (int d = 0; d < 12; d++) s += em[d] * weash[l * ED * HEADS + d * HEADS + h];
        aloop[t] = s;
    }
}

// ---------------------------------------------------------------------------
// Per-edge attention terms for ALL layers, permuted into CSR order, bf16x4.
// Coalesced csr walk; random ea[eid] read (L3-absorbed); coalesced writes.
// Layer-static -> computed once per call, read coalesced by node_kernel x4.
// ---------------------------------------------------------------------------
__launch_bounds__(256)
__global__ void aedgep_kernel(const int2* __restrict__ csr, const float* __restrict__ ea,
                              const float* __restrict__ wea_all, const float* __restrict__ aloop,
                              uint2* __restrict__ aecsr) {
    __shared__ float wsh[LAYERS * ED * HEADS];   // 768 B
    __shared__ float lsh[LAYERS * HEADS];
    int t = threadIdx.x;
    if (t < LAYERS * ED * HEADS) wsh[t] = wea_all[t];
    if (t < LAYERS * HEADS) lsh[t] = aloop[t];
    __syncthreads();
    int i = blockIdx.x * 256 + t;
    if (i >= N_ETOT) return;
    int e = csr[i].y;
    float a[LAYERS][4];
    if (e < N_EDGES) {
        float er[12];
        const float* ep = ea + (size_t)e * ED;
#pragma unroll
        for (int d = 0; d < 12; d++) er[d] = ep[d];
#pragma unroll
        for (int l = 0; l < LAYERS; l++) {
#pragma unroll
            for (int h = 0; h < 4; h++) {
                float s = 0.f;
#pragma unroll
                for (int d = 0; d < 12; d++) s += er[d] * wsh[l * 48 + d * 4 + h];
                a[l][h] = s;
            }
        }
    } else {
#pragma unroll
        for (int l = 0; l < LAYERS; l++)
#pragma unroll
            for (int h = 0; h < 4; h++) a[l][h] = lsh[l * 4 + h];
    }
#pragma unroll
    for (int l = 0; l < LAYERS; l++)
        aecsr[(size_t)l * N_ETOT + i] =
            make_uint2(bf16pair(a[l][0], a[l][1]), bf16pair(a[l][2], a[l][3]));
}

// ---------------------------------------------------------------------------
// Pack all layer weights W[l][k][n] (f32) into per-lane MFMA B-fragment order.
// ---------------------------------------------------------------------------
__global__ void packW_kernel(const float* __restrict__ W, unsigned short* __restrict__ wb) {
    int idx = blockIdx.x * 256 + threadIdx.x;
    if (idx >= LAYERS * HID * HID) return;
    int l = idx >> 14;
    int k = (idx >> 7) & 127;
    int n = idx & 127;
    unsigned u = __float_as_uint(W[idx]);
    u = (u + 0x7FFFu + ((u >> 16) & 1u)) >> 16;
    int kt = k >> 5, q = (k & 31) >> 3, j = k & 7;
    int nt = n >> 4, c = n & 15;
    int lane = q * 16 + c;
    wb[(size_t)l * 16384 + ((size_t)(kt * 8 + nt) * 64 + lane) * 8 + j] = (unsigned short)u;
}

// ---------------------------------------------------------------------------
// Initial projection GEMM (f32 SIMD): h = relu(x @ Wp + bp); dual f32/bf16 out.
// ---------------------------------------------------------------------------
__launch_bounds__(256)
__global__ void gemm0_kernel(const float* __restrict__ A, const float* __restrict__ B,
                             const float* __restrict__ bias, float* __restrict__ C,
                             unsigned* __restrict__ Cb) {
    constexpr int K = 64;
    __shared__ float Bs[K * 128];
    int t = threadIdx.x;
    const float4* B4 = (const float4*)B;
    float4* Bs4 = (float4*)Bs;
#pragma unroll
    for (int i = t; i < K * 32; i += 256) Bs4[i] = B4[i];
    __syncthreads();

    int c0 = (t & 15) * 8;
    int r0 = (t >> 4) * 4;
    int rbase = blockIdx.x * 64 + r0;

    float acc[4][8];
#pragma unroll
    for (int j = 0; j < 4; j++)
#pragma unroll
        for (int c = 0; c < 8; c++) acc[j][c] = 0.f;

    const float4* A4 = (const float4*)A;
    int rg[4];
#pragma unroll
    for (int j = 0; j < 4; j++) rg[j] = min(rbase + j, N_NODES - 1);

    for (int kk = 0; kk < K; kk += 4) {
        float4 av[4];
#pragma unroll
        for (int j = 0; j < 4; j++) av[j] = A4[(size_t)rg[j] * (K / 4) + (kk >> 2)];
        float a_arr[4][4];
#pragma unroll
        for (int j = 0; j < 4; j++) {
            a_arr[j][0] = av[j].x; a_arr[j][1] = av[j].y;
            a_arr[j][2] = av[j].z; a_arr[j][3] = av[j].w;
        }
#pragma unroll
        for (int jj = 0; jj < 4; jj++) {
            float4 b0 = Bs4[(kk + jj) * 32 + (c0 >> 2)];
            float4 b1 = Bs4[(kk + jj) * 32 + (c0 >> 2) + 1];
#pragma unroll
            for (int j = 0; j < 4; j++) {
                float a = a_arr[j][jj];
                acc[j][0] += a * b0.x; acc[j][1] += a * b0.y;
                acc[j][2] += a * b0.z; acc[j][3] += a * b0.w;
                acc[j][4] += a * b1.x; acc[j][5] += a * b1.y;
                acc[j][6] += a * b1.z; acc[j][7] += a * b1.w;
            }
        }
    }

#pragma unroll
    for (int j = 0; j < 4; j++) {
        int r = rbase + j;
        if (r < N_NODES) {
            float o[8];
#pragma unroll
            for (int c = 0; c < 8; c++) o[c] = fmaxf(acc[j][c] + bias[c0 + c], 0.f);
            ((float4*)(C + (size_t)r * 128 + c0))[0] = make_float4(o[0], o[1], o[2], o[3]);
            ((float4*)(C + (size_t)r * 128 + c0 + 4))[0] = make_float4(o[4], o[5], o[6], o[7]);
            uint4 pk;
            pk.x = bf16pair(o[0], o[1]); pk.y = bf16pair(o[2], o[3]);
            pk.z = bf16pair(o[4], o[5]); pk.w = bf16pair(o[6], o[7]);
            ((uint4*)(Cb + (size_t)r * 64 + (c0 >> 1)))[0] = pk;
        }
    }
}

// ---------------------------------------------------------------------------
// Layer projection GEMM via MFMA bf16 + fused attention dots (see R5 notes).
// ---------------------------------------------------------------------------
__launch_bounds__(256)
__global__ void gemm_mfma_kernel(const unsigned short* __restrict__ hAb,
                                 const unsigned short* __restrict__ wb,
                                 const float* __restrict__ att_s,
                                 const float* __restrict__ att_d,
                                 unsigned* __restrict__ xpb,
                                 float* __restrict__ asrc, float* __restrict__ adst) {
    __shared__ float lds[4][16][129];
    int t = threadIdx.x;
    int w = t >> 6, lane = t & 63;
    int rbase = blockIdx.x * 64 + w * 16;
    int mrow = lane & 15, quad = lane >> 4;

    floatx4 acc[8];
#pragma unroll
    for (int nt = 0; nt < 8; nt++) acc[nt] = (floatx4){0.f, 0.f, 0.f, 0.f};

    int arow = min(rbase + mrow, N_NODES - 1);
    const short8* wb8 = (const short8*)wb;
#pragma unroll
    for (int kt = 0; kt < 4; kt++) {
        short8 afrag = *(const short8*)(hAb + (size_t)arow * 128 + kt * 32 + quad * 8);
#pragma unroll
        for (int nt = 0; nt < 8; nt++) {
            short8 bfrag = wb8[(kt * 8 + nt) * 64 + lane];
            acc[nt] = __builtin_amdgcn_mfma_f32_16x16x32_bf16(afrag, bfrag, acc[nt], 0, 0, 0);
        }
    }

    // C layout -> LDS (per-wave region; same-wave read below, no barrier)
#pragma unroll
    for (int nt = 0; nt < 8; nt++)
#pragma unroll
        for (int rr = 0; rr < 4; rr++)
            lds[w][quad * 4 + rr][nt * 16 + mrow] = acc[nt][rr];

    int row = lane >> 2, h = lane & 3;
    int r = rbase + row;
    float vals[32];
    float ps = 0.f, pd = 0.f;
#pragma unroll
    for (int c = 0; c < 32; c++) {
        float v = lds[w][row][h * 32 + c];
        vals[c] = v;
        ps += v * att_s[h * 32 + c];
        pd += v * att_d[h * 32 + c];
    }
    if (r < N_NODES) {
        unsigned* dstp = xpb + (size_t)r * 64 + h * 16;
#pragma unroll
        for (int qq = 0; qq < 4; qq++) {
            uint4 o;
            o.x = bf16pair(vals[qq * 8 + 0], vals[qq * 8 + 1]);
            o.y = bf16pair(vals[qq * 8 + 2], vals[qq * 8 + 3]);
            o.z = bf16pair(vals[qq * 8 + 4], vals[qq * 8 + 5]);
            o.w = bf16pair(vals[qq * 8 + 6], vals[qq * 8 + 7]);
            ((uint4*)dstp)[qq] = o;
        }
        asrc[r * 4 + h] = ps;
        adst[r * 4 + h] = pd;
    }
}

// ---------------------------------------------------------------------------
// Single-pass aggregation with ON-THE-FLY softmax weights. One wave per node,
// quarter-wave per edge; lane = 16*sub + sl, head h = sl>>2. Per edge:
// csr int2 + aecsr bf16x4 (both coalesced), asrc[s] random (800 KB, L2-hot),
// adst[n] wave-uniform, xpb row gather (random 256 B). 16 edges in flight.
// ---------------------------------------------------------------------------
__launch_bounds__(256)
__global__ void node_kernel(const uint2* __restrict__ aecsr, const float* __restrict__ asrc,
                            const float* __restrict__ adst, const int* __restrict__ rowp,
                            const int2* __restrict__ csr, const unsigned* __restrict__ xpb,
                            float* __restrict__ out) {
    int gw = (blockIdx.x * blockDim.x + threadIdx.x) >> 6;
    int lane = threadIdx.x & 63;
    if (gw >= N_NODES) return;
    int sub = lane >> 4;   // edge slot 0..3
    int sl  = lane & 15;   // channel octet
    int h   = sl >> 2;     // head
    int beg = rowp[gw], end = rowp[gw + 1];
    const uint4* xp4 = (const uint4*)xpb;   // 16 uint4 per 128-ch row
    float adh = adst[gw * 4 + h];

    float a[8];
#pragma unroll
    for (int c = 0; c < 8; c++) a[c] = 0.f;
    float den = 0.f;

#define PROC(JJ)                                                                 \
    {                                                                            \
        int2 se = csr[JJ];                                                       \
        uint2 ae = aecsr[JJ];                                                    \
        unsigned aw = (h & 2) ? ae.y : ae.x;                                     \
        float aeh = __uint_as_float((h & 1) ? (aw & 0xFFFF0000u) : (aw << 16));  \
        float ash = asrc[se.x * 4 + h];                                          \
        uint4 v = xp4[(size_t)se.x * 16 + sl];                                   \
        float lg = ash + adh + aeh;                                              \
        lg = (lg > 0.f) ? lg : 0.2f * lg;                                        \
        float ex = __expf(fminf(lg, 60.f));                                      \
        a[0] += ex * __uint_as_float(v.x << 16);                                 \
        a[1] += ex * __uint_as_float(v.x & 0xFFFF0000u);                         \
        a[2] += ex * __uint_as_float(v.y << 16);                                 \
        a[3] += ex * __uint_as_float(v.y & 0xFFFF0000u);                         \
        a[4] += ex * __uint_as_float(v.z << 16);                                 \
        a[5] += ex * __uint_as_float(v.z & 0xFFFF0000u);                         \
        a[6] += ex * __uint_as_float(v.w << 16);                                 \
        a[7] += ex * __uint_as_float(v.w & 0xFFFF0000u);                         \
        den += ex;                                                               \
    }

    int j = beg + sub;
    for (; j + 12 < end; j += 16) {
        PROC(j); PROC(j + 4); PROC(j + 8); PROC(j + 12);
    }
    for (; j < end; j += 4) PROC(j);
#undef PROC

    // reduce over the 4 quarter-waves
#pragma unroll
    for (int c = 0; c < 8; c++) {
        a[c] += __shfl_xor(a[c], 16);
        a[c] += __shfl_xor(a[c], 32);
    }
    den += __shfl_xor(den, 16);
    den += __shfl_xor(den, 32);
    float inv = 1.0f / den;   // deg >= 1 (self loop)
    if (sub == 0) {
        float* op = out + (size_t)gw * 128 + sl * 8;
        ((float4*)op)[0] = make_float4(a[0] * inv, a[1] * inv, a[2] * inv, a[3] * inv);
        ((float4*)op)[1] = make_float4(a[4] * inv, a[5] * inv, a[6] * inv, a[7] * inv);
    }
}

// ---------------------------------------------------------------------------
// BatchNorm statistics + fused update (BN finalize in-block, relu, residual,
// bf16 repack of h for the next layer's MFMA GEMM)
// ---------------------------------------------------------------------------
__launch_bounds__(256)
__global__ void bnstats_kernel(const float* __restrict__ h, float* __restrict__ bnsum,
                               float* __restrict__ bnsum2) {
    __shared__ float ls[256], ls2[256];
    int t = threadIdx.x;
    int c = t & 127, half = t >> 7;
    int r0 = blockIdx.x * 128;
    float s = 0.f, s2 = 0.f;
    int rend = min(r0 + 128, N_NODES);
    for (int r = r0 + half; r < rend; r += 2) {
        float v = h[(size_t)r * 128 + c];
        s += v; s2 += v * v;
    }
    ls[t] = s; ls2[t] = s2;
    __syncthreads();
    if (half == 0) {
        s += ls[t + 128]; s2 += ls2[t + 128];
        atomicAdd(&bnsum[c], s);
        atomicAdd(&bnsum2[c], s2);
    }
}

__launch_bounds__(256)
__global__ void update_kernel(const float* __restrict__ outb, const float* __restrict__ bnsum,
                              const float* __restrict__ bnsum2, const float* __restrict__ gamma,
                              const float* __restrict__ beta, const float* __restrict__ hA,
                              float* __restrict__ dst, unsigned* __restrict__ dstb,
                              int add_res) {
    __shared__ float sc_s[128], sh_s[128];
    int t = threadIdx.x;
    if (t < 128) {
        float mu = bnsum[t] / (float)N_NODES;
        float var = bnsum2[t] / (float)N_NODES - mu * mu;
        float inv = rsqrtf(var + BN_EPS);
        float g = gamma[t] * inv;
        sc_s[t] = g;
        sh_s[t] = beta[t] - mu * g;
    }
    __syncthreads();
    int i = blockIdx.x * blockDim.x + t;
    if (i >= N_NODES * 32) return;
    int c4 = (i & 31) * 4;
    float4 o = ((const float4*)outb)[i];
    float4 v;
    v.x = fmaxf(o.x * sc_s[c4 + 0] + sh_s[c4 + 0], 0.f);
    v.y = fmaxf(o.y * sc_s[c4 + 1] + sh_s[c4 + 1], 0.f);
    v.z = fmaxf(o.z * sc_s[c4 + 2] + sh_s[c4 + 2], 0.f);
    v.w = fmaxf(o.w * sc_s[c4 + 3] + sh_s[c4 + 3], 0.f);
    if (add_res) {
        float4 hh = ((const float4*)hA)[i];
        v.x += hh.x; v.y += hh.y; v.z += hh.z; v.w += hh.w;
    }
    ((float4*)dst)[i] = v;
    ((uint2*)dstb)[i] = make_uint2(bf16pair(v.x, v.y), bf16pair(v.z, v.w));
}

// ---------------------------------------------------------------------------
extern "C" void kernel_launch(void* const* d_in, const int* in_sizes, int n_in,
                              void* d_out, int out_size, void* d_ws, size_t ws_size,
                              hipStream_t stream) {
    const float* x          = (const float*)d_in[0];
    const int*   edge_index = (const int*)d_in[1];
    const float* edge_attr  = (const float*)d_in[2];
    const float* Wp         = (const float*)d_in[3];
    const float* bp         = (const float*)d_in[4];
    const float* W          = (const float*)d_in[5];
    const float* We         = (const float*)d_in[6];
    const float* att_src    = (const float*)d_in[7];
    const float* att_dst    = (const float*)d_in[8];
    const float* att_edge   = (const float*)d_in[9];
    // d_in[10] bias: absorbed exactly by training-mode BN -> skipped
    const float* gamma      = (const float*)d_in[11];
    const float* beta       = (const float*)d_in[12];
    float* outp = (float*)d_out;

    const int* ei_src = edge_index;
    const int* ei_dst = edge_index + N_EDGES;

    char* p = (char*)d_ws;
    auto alloc = [&](size_t nbytes) {
        char* r = p;
        p += (nbytes + 255) & ~(size_t)255;
        return r;
    };
    // zero-initialized region: hist | easum | bnsum(4 layers x 256)
    int*   hist     = (int*)alloc((size_t)N_NODES * 4);
    float* easum    = (float*)alloc(16 * 4);
    float* bnsumall = (float*)alloc((size_t)LAYERS * 256 * 4);
    size_t zero_bytes = (char*)(bnsumall + LAYERS * 256) - (char*)hist;

    float* hA       = (float*)alloc((size_t)N_NODES * 128 * 4);
    unsigned* hAb   = (unsigned*)alloc((size_t)N_NODES * 64 * 4);   // bf16x2, GEMM A feed
    unsigned* xpb   = (unsigned*)alloc((size_t)N_NODES * 64 * 4);   // bf16x2, gather payload
    float* outb     = (float*)alloc((size_t)N_NODES * 128 * 4);
    float* asrc     = (float*)alloc((size_t)N_NODES * 4 * 4);
    float* adst     = (float*)alloc((size_t)N_NODES * 4 * 4);
    float* wea_all  = (float*)alloc((LAYERS * 48 + 16) * 4);
    float* aloop    = wea_all + LAYERS * 48;
    unsigned short* wb = (unsigned short*)alloc((size_t)LAYERS * 16384 * 2);
    int* rowp       = (int*)alloc(((size_t)N_NODES + 1) * 4);
    int* cursor     = (int*)alloc((size_t)N_NODES * 4);
    int2* csr       = (int2*)alloc((size_t)N_ETOT * 8);
    uint2* aecsr    = (uint2*)alloc((size_t)LAYERS * N_ETOT * 8);   // bf16x4 per edge/layer
    int* bsum       = (int*)alloc(256 * 4);
    int* boff       = (int*)alloc(256 * 4);

    const int EB = (N_ETOT + 255) / 256;

    (void)hipMemsetAsync(hist, 0, zero_bytes, stream);

    // ---- CSR build (graph fixed across layers) ----
    hist_kernel<<<EB, 256, 0, stream>>>(ei_dst, hist);
    blocksum_kernel<<<SCAN_BLK, 256, 0, stream>>>(hist, bsum);
    bscan_kernel<<<1, 256, 0, stream>>>(bsum, boff, rowp);
    rowp_kernel<<<SCAN_BLK, 256, 0, stream>>>(hist, boff, rowp, cursor);
    scatter_kernel<<<EB, 256, 0, stream>>>(ei_src, ei_dst, cursor, csr);

    // ---- edge-attr mean + folded matrices + W pre-pack + CSR-ordered
    //      per-edge attention terms for all layers ----
    eamean_kernel<<<256, 256, 0, stream>>>(edge_attr, easum);
    prep_kernel<<<1, 256, 0, stream>>>(easum, We, att_edge, wea_all, aloop);
    packW_kernel<<<(LAYERS * HID * HID + 255) / 256, 256, 0, stream>>>(W, wb);
    aedgep_kernel<<<EB, 256, 0, stream>>>(csr, edge_attr, wea_all, aloop, aecsr);

    // ---- initial projection (f32 SIMD, bias+relu, dual f32/bf16 store) ----
    gemm0_kernel<<<(N_NODES + 63) / 64, 256, 0, stream>>>(x, Wp, bp, hA, hAb);

    for (int l = 0; l < LAYERS; l++) {
        float* bnsum  = bnsumall + l * 256;
        float* bnsum2 = bnsum + 128;
        gemm_mfma_kernel<<<(N_NODES + 63) / 64, 256, 0, stream>>>(
            (const unsigned short*)hAb, wb + (size_t)l * 16384,
            att_src + l * 128, att_dst + l * 128, xpb, asrc, adst);
        node_kernel<<<(N_NODES + 3) / 4, 256, 0, stream>>>(
            aecsr + (size_t)l * N_ETOT, asrc, adst, rowp, csr, xpb, outb);
        bnstats_kernel<<<(N_NODES + 127) / 128, 256, 0, stream>>>(outb, bnsum, bnsum2);
        float* dst = (l == LAYERS - 1) ? outp : hA;
        update_kernel<<<(N_NODES * 32 + 255) / 256, 256, 0, stream>>>(
            outb, bnsum, bnsum2, gamma + l * 128, beta + l * 128, hA, dst, hAb,
            (l > 0) ? 1 : 0);
    }
}

// Round 11
// 638.361 us; speedup vs baseline: 2.0343x; 1.0540x over previous
//
#include <hip/hip_runtime.h>

// Problem constants (match reference setup_inputs)
constexpr int N_NODES = 50000;
constexpr int N_EDGES = 800000;
constexpr int N_ETOT  = N_EDGES + N_NODES;   // with self loops
constexpr int HID     = 128;
constexpr int HEADS   = 4;
constexpr int ED      = 12;
constexpr int LAYERS  = 4;
constexpr float BN_EPS = 1e-5f;
constexpr int SCAN_BLK = (N_NODES + 255) / 256;   // 196
constexpr int EB = (N_ETOT + 255) / 256;          // 3321 edge blocks
constexpr int GB = (N_NODES + 63) / 64;           // 782 gemm blocks
constexpr int WB = (LAYERS * HID * HID + 255) / 256;  // 256 packW blocks

typedef __attribute__((ext_vector_type(8))) short short8;
typedef __attribute__((ext_vector_type(4))) float floatx4;

__device__ inline unsigned bf16pair(float a, float b) {
    unsigned ua = __float_as_uint(a), ub = __float_as_uint(b);
    ua = (ua + 0x7FFFu + ((ua >> 16) & 1u)) >> 16;
    ub = (ub + 0x7FFFu + ((ub >> 16) & 1u)) >> 16;
    return ua | (ub << 16);
}

// ---------------------------------------------------------------------------
// pre1: [hist | eamean | packW] — independent preamble work, one dispatch.
// ---------------------------------------------------------------------------
__launch_bounds__(256)
__global__ void pre1_kernel(const int* __restrict__ dst, int* __restrict__ hist,
                            const float* __restrict__ ea, float* __restrict__ easum,
                            const float* __restrict__ W, unsigned short* __restrict__ wb) {
    __shared__ float ls[12];
    int bid = blockIdx.x, t = threadIdx.x;
    if (bid < EB) {
        int e = bid * 256 + t;
        if (e < N_ETOT) {
            int d = (e < N_EDGES) ? dst[e] : (e - N_EDGES);
            atomicAdd(&hist[d], 1);
        }
    } else if (bid < EB + 256) {
        int b2 = bid - EB;
        if (t < 12) ls[t] = 0.f;
        __syncthreads();
        float loc[12];
#pragma unroll
        for (int d = 0; d < 12; d++) loc[d] = 0.f;
        for (int e = b2 * 256 + t; e < N_EDGES; e += 256 * 256) {
            const float* er = ea + (size_t)e * ED;
#pragma unroll
            for (int d = 0; d < 12; d++) loc[d] += er[d];
        }
#pragma unroll
        for (int d = 0; d < 12; d++) atomicAdd(&ls[d], loc[d]);
        __syncthreads();
        if (t < 12) atomicAdd(&easum[t], ls[t]);
    } else {
        int idx = (bid - EB - 256) * 256 + t;
        if (idx < LAYERS * HID * HID) {
            int l = idx >> 14;
            int k = (idx >> 7) & 127;
            int n = idx & 127;
            unsigned u = __float_as_uint(W[idx]);
            u = (u + 0x7FFFu + ((u >> 16) & 1u)) >> 16;
            int kt = k >> 5, q = (k & 31) >> 3, j = k & 7;
            int nt = n >> 4, c = n & 15;
            int lane = q * 16 + c;
            wb[(size_t)l * 16384 + ((size_t)(kt * 8 + nt) * 64 + lane) * 8 + j] =
                (unsigned short)u;
        }
    }
}

__global__ void blocksum_kernel(const int* __restrict__ hist, int* __restrict__ bsum) {
    __shared__ int sd[256];
    int t = threadIdx.x;
    int n = blockIdx.x * 256 + t;
    sd[t] = (n < N_NODES) ? hist[n] : 0;
    __syncthreads();
#pragma unroll
    for (int off = 128; off; off >>= 1) {
        if (t < off) sd[t] += sd[t + off];
        __syncthreads();
    }
    if (t == 0) bsum[blockIdx.x] = sd[0];
}

// ---------------------------------------------------------------------------
// pre2: [bscan | prep] — block 0 scans block sums; block 1 folds We/att_edge.
// ---------------------------------------------------------------------------
__launch_bounds__(256)
__global__ void pre2_kernel(const int* __restrict__ bsum, int* __restrict__ boff,
                            int* __restrict__ rowp, const float* __restrict__ easum,
                            const float* __restrict__ We, const float* __restrict__ att_edge,
                            float* __restrict__ wea_all, float* __restrict__ aloop) {
    int t = threadIdx.x;
    if (blockIdx.x == 0) {
        __shared__ int sd[256];
        int v = (t < SCAN_BLK) ? bsum[t] : 0;
        sd[t] = v;
        __syncthreads();
#pragma unroll
        for (int off = 1; off < 256; off <<= 1) {
            int u = (t >= off) ? sd[t - off] : 0;
            __syncthreads();
            sd[t] += u;
            __syncthreads();
        }
        if (t < SCAN_BLK) boff[t] = sd[t] - v;
        if (t == 255) rowp[N_NODES] = sd[255];
    } else {
        __shared__ float em[12];
        __shared__ float weash[LAYERS * ED * HEADS];
        if (t < 12) em[t] = easum[t] / (float)N_EDGES;
        if (t < LAYERS * ED * HEADS) {
            int l = t / (ED * HEADS);
            int r = t % (ED * HEADS);
            int d = r / HEADS;
            int h = r % HEADS;
            float sum = 0.f;
#pragma unroll
            for (int c = 0; c < 32; c++)
                sum += We[((size_t)(l * ED + d)) * HID + h * 32 + c] *
                       att_edge[(l * HEADS + h) * 32 + c];
            wea_all[t] = sum;
            weash[t] = sum;
        }
        __syncthreads();
        if (t < LAYERS * HEADS) {
            int l = t / HEADS, h = t % HEADS;
            float s = 0.f;
#pragma unroll
            for (int d = 0; d < 12; d++) s += em[d] * weash[l * ED * HEADS + d * HEADS + h];
            aloop[t] = s;
        }
    }
}

__global__ void rowp_kernel(const int* __restrict__ hist, const int* __restrict__ boff,
                            int* __restrict__ rowp, int* __restrict__ cursor) {
    __shared__ int sd[256];
    int t = threadIdx.x;
    int n = blockIdx.x * 256 + t;
    int v = (n < N_NODES) ? hist[n] : 0;
    sd[t] = v;
    __syncthreads();
#pragma unroll
    for (int off = 1; off < 256; off <<= 1) {
        int u = (t >= off) ? sd[t - off] : 0;
        __syncthreads();
        sd[t] += u;
        __syncthreads();
    }
    if (n < N_NODES) {
        int excl = sd[t] - v + boff[blockIdx.x];
        rowp[n] = excl;
        cursor[n] = excl;
    }
}

// ---------------------------------------------------------------------------
// pre3: [scatter | gemm0] — independent; scatter's ~57us random-line-write
// floor (R9 measured) hides under gemm0's compute.
// ---------------------------------------------------------------------------
__launch_bounds__(256)
__global__ void pre3_kernel(const int* __restrict__ src, const int* __restrict__ dst,
                            int* __restrict__ cursor, int2* __restrict__ csr,
                            const float* __restrict__ A, const float* __restrict__ B,
                            const float* __restrict__ bias, float* __restrict__ C,
                            unsigned* __restrict__ Cb) {
    __shared__ float Bs[64 * 128];
    int t = threadIdx.x;
    if (blockIdx.x < EB) {
        int e = blockIdx.x * 256 + t;
        if (e >= N_ETOT) return;
        int s, d;
        if (e < N_EDGES) { s = src[e]; d = dst[e]; }
        else             { s = d = e - N_EDGES; }
        int pos = atomicAdd(&cursor[d], 1);
        csr[pos] = make_int2(s, e);
        return;
    }
    // ---- gemm0: h = relu(x @ Wp + bp), dual f32/bf16 out ----
    constexpr int K = 64;
    int bid = blockIdx.x - EB;
    const float4* B4 = (const float4*)B;
    float4* Bs4 = (float4*)Bs;
#pragma unroll
    for (int i = t; i < K * 32; i += 256) Bs4[i] = B4[i];
    __syncthreads();

    int c0 = (t & 15) * 8;
    int r0 = (t >> 4) * 4;
    int rbase = bid * 64 + r0;

    float acc[4][8];
#pragma unroll
    for (int j = 0; j < 4; j++)
#pragma unroll
        for (int c = 0; c < 8; c++) acc[j][c] = 0.f;

    const float4* A4 = (const float4*)A;
    int rg[4];
#pragma unroll
    for (int j = 0; j < 4; j++) rg[j] = min(rbase + j, N_NODES - 1);

    for (int kk = 0; kk < K; kk += 4) {
        float4 av[4];
#pragma unroll
        for (int j = 0; j < 4; j++) av[j] = A4[(size_t)rg[j] * (K / 4) + (kk >> 2)];
        float a_arr[4][4];
#pragma unroll
        for (int j = 0; j < 4; j++) {
            a_arr[j][0] = av[j].x; a_arr[j][1] = av[j].y;
            a_arr[j][2] = av[j].z; a_arr[j][3] = av[j].w;
        }
#pragma unroll
        for (int jj = 0; jj < 4; jj++) {
            float4 b0 = Bs4[(kk + jj) * 32 + (c0 >> 2)];
            float4 b1 = Bs4[(kk + jj) * 32 + (c0 >> 2) + 1];
#pragma unroll
            for (int j = 0; j < 4; j++) {
                float a = a_arr[j][jj];
                acc[j][0] += a * b0.x; acc[j][1] += a * b0.y;
                acc[j][2] += a * b0.z; acc[j][3] += a * b0.w;
                acc[j][4] += a * b1.x; acc[j][5] += a * b1.y;
                acc[j][6] += a * b1.z; acc[j][7] += a * b1.w;
            }
        }
    }

#pragma unroll
    for (int j = 0; j < 4; j++) {
        int r = rbase + j;
        if (r < N_NODES) {
            float o[8];
#pragma unroll
            for (int c = 0; c < 8; c++) o[c] = fmaxf(acc[j][c] + bias[c0 + c], 0.f);
            ((float4*)(C + (size_t)r * 128 + c0))[0] = make_float4(o[0], o[1], o[2], o[3]);
            ((float4*)(C + (size_t)r * 128 + c0 + 4))[0] = make_float4(o[4], o[5], o[6], o[7]);
            uint4 pk;
            pk.x = bf16pair(o[0], o[1]); pk.y = bf16pair(o[2], o[3]);
            pk.z = bf16pair(o[4], o[5]); pk.w = bf16pair(o[6], o[7]);
            ((uint4*)(Cb + (size_t)r * 64 + (c0 >> 1)))[0] = pk;
        }
    }
}

// ---------------------------------------------------------------------------
// pre4: [aedgep | gemm_mfma layer 0]. aedgep: per-edge attention terms for all
// layers in CSR order (bf16x4); gemm: plain MFMA projection reading hAb.
// ---------------------------------------------------------------------------
__launch_bounds__(256)
__global__ void pre4_kernel(const int2* __restrict__ csr, const float* __restrict__ ea,
                            const float* __restrict__ wea_all, const float* __restrict__ aloop,
                            uint2* __restrict__ aecsr,
                            const unsigned short* __restrict__ hAb,
                            const unsigned short* __restrict__ wb,
                            const float* __restrict__ att_s, const float* __restrict__ att_d,
                            unsigned* __restrict__ xpb,
                            float* __restrict__ asrc, float* __restrict__ adst) {
    __shared__ float smem[4 * 16 * 129];   // 33 KB, shared by both branches
    int t = threadIdx.x;
    if (blockIdx.x < EB) {
        float* wsh = smem;            // 192
        float* lsh = smem + 192;      // 16
        if (t < LAYERS * ED * HEADS) wsh[t] = wea_all[t];
        if (t < LAYERS * HEADS) lsh[t] = aloop[t];
        __syncthreads();
        int i = blockIdx.x * 256 + t;
        if (i >= N_ETOT) return;
        int e = csr[i].y;
        float a[LAYERS][4];
        if (e < N_EDGES) {
            float er[12];
            const float* ep = ea + (size_t)e * ED;
#pragma unroll
            for (int d = 0; d < 12; d++) er[d] = ep[d];
#pragma unroll
            for (int l = 0; l < LAYERS; l++)
#pragma unroll
                for (int h = 0; h < 4; h++) {
                    float s = 0.f;
#pragma unroll
                    for (int d = 0; d < 12; d++) s += er[d] * wsh[l * 48 + d * 4 + h];
                    a[l][h] = s;
                }
        } else {
#pragma unroll
            for (int l = 0; l < LAYERS; l++)
#pragma unroll
                for (int h = 0; h < 4; h++) a[l][h] = lsh[l * 4 + h];
        }
#pragma unroll
        for (int l = 0; l < LAYERS; l++)
            aecsr[(size_t)l * N_ETOT + i] =
                make_uint2(bf16pair(a[l][0], a[l][1]), bf16pair(a[l][2], a[l][3]));
        return;
    }
    // ---- plain MFMA projection (layer 0), A from hAb ----
    int bid = blockIdx.x - EB;
    float (*lds)[16][129] = (float (*)[16][129])smem;
    int w = t >> 6, lane = t & 63;
    int rbase = bid * 64 + w * 16;
    int mrow = lane & 15, quad = lane >> 4;

    floatx4 acc[8];
#pragma unroll
    for (int nt = 0; nt < 8; nt++) acc[nt] = (floatx4){0.f, 0.f, 0.f, 0.f};

    int arow = min(rbase + mrow, N_NODES - 1);
    const short8* wb8 = (const short8*)wb;
#pragma unroll
    for (int kt = 0; kt < 4; kt++) {
        short8 afrag = *(const short8*)(hAb + (size_t)arow * 128 + kt * 32 + quad * 8);
#pragma unroll
        for (int nt = 0; nt < 8; nt++) {
            short8 bfrag = wb8[(kt * 8 + nt) * 64 + lane];
            acc[nt] = __builtin_amdgcn_mfma_f32_16x16x32_bf16(afrag, bfrag, acc[nt], 0, 0, 0);
        }
    }
#pragma unroll
    for (int nt = 0; nt < 8; nt++)
#pragma unroll
        for (int rr = 0; rr < 4; rr++)
            lds[w][quad * 4 + rr][nt * 16 + mrow] = acc[nt][rr];

    int row = lane >> 2, h = lane & 3;
    int r = rbase + row;
    float vals[32];
    float ps = 0.f, pd = 0.f;
#pragma unroll
    for (int c = 0; c < 32; c++) {
        float v = lds[w][row][h * 32 + c];
        vals[c] = v;
        ps += v * att_s[h * 32 + c];
        pd += v * att_d[h * 32 + c];
    }
    if (r < N_NODES) {
        unsigned* dstp = xpb + (size_t)r * 64 + h * 16;
#pragma unroll
        for (int qq = 0; qq < 4; qq++) {
            uint4 o;
            o.x = bf16pair(vals[qq * 8 + 0], vals[qq * 8 + 1]);
            o.y = bf16pair(vals[qq * 8 + 2], vals[qq * 8 + 3]);
            o.z = bf16pair(vals[qq * 8 + 4], vals[qq * 8 + 5]);
            o.w = bf16pair(vals[qq * 8 + 6], vals[qq * 8 + 7]);
            ((uint4*)dstp)[qq] = o;
        }
        asrc[r * 4 + h] = ps;
        adst[r * 4 + h] = pd;
    }
}

// ---------------------------------------------------------------------------
// Fused BN-update + MFMA projection (layers 1..3). Prologue per lane: read
// outb chunk, apply BN(scale/shift from bnsum in LDS) + relu (+ residual hA),
// write new hA (owner lanes only — avoids row-(N-1) clamp race), pack bf16
// A-fragment in registers. Replaces update_kernel + hAb round-trip.
// ---------------------------------------------------------------------------
template <int ADD>
__launch_bounds__(256)
__global__ void gemm_fused_kernel(const float* __restrict__ outb,
                                  const float* __restrict__ bnsum,
                                  const float* __restrict__ bnsum2,
                                  const float* __restrict__ gamma,
                                  const float* __restrict__ beta,
                                  float* __restrict__ hA,
                                  const unsigned short* __restrict__ wb,
                                  const float* __restrict__ att_s,
                                  const float* __restrict__ att_d,
                                  unsigned* __restrict__ xpb,
                                  float* __restrict__ asrc, float* __restrict__ adst) {
    __shared__ float lds[4][16][129];
    __shared__ float sc_s[128], sh_s[128];
    int t = threadIdx.x;
    if (t < 128) {
        float mu = bnsum[t] / (float)N_NODES;
        float var = bnsum2[t] / (float)N_NODES - mu * mu;
        float inv = rsqrtf(var + BN_EPS);
        float g = gamma[t] * inv;
        sc_s[t] = g;
        sh_s[t] = beta[t] - mu * g;
    }
    __syncthreads();

    int w = t >> 6, lane = t & 63;
    int rbase = blockIdx.x * 64 + w * 16;
    int mrow = lane & 15, quad = lane >> 4;
    int arow = rbase + mrow;
    bool owner = arow < N_NODES;
    int ar = min(arow, N_NODES - 1);

    floatx4 acc[8];
#pragma unroll
    for (int nt = 0; nt < 8; nt++) acc[nt] = (floatx4){0.f, 0.f, 0.f, 0.f};

    const short8* wb8 = (const short8*)wb;
#pragma unroll
    for (int kt = 0; kt < 4; kt++) {
        int cb = kt * 32 + quad * 8;
        const float4* ob = (const float4*)(outb + (size_t)ar * 128 + cb);
        float4 o0 = ob[0], o1 = ob[1];
        float v[8];
        v[0] = fmaxf(o0.x * sc_s[cb + 0] + sh_s[cb + 0], 0.f);
        v[1] = fmaxf(o0.y * sc_s[cb + 1] + sh_s[cb + 1], 0.f);
        v[2] = fmaxf(o0.z * sc_s[cb + 2] + sh_s[cb + 2], 0.f);
        v[3] = fmaxf(o0.w * sc_s[cb + 3] + sh_s[cb + 3], 0.f);
        v[4] = fmaxf(o1.x * sc_s[cb + 4] + sh_s[cb + 4], 0.f);
        v[5] = fmaxf(o1.y * sc_s[cb + 5] + sh_s[cb + 5], 0.f);
        v[6] = fmaxf(o1.z * sc_s[cb + 6] + sh_s[cb + 6], 0.f);
        v[7] = fmaxf(o1.w * sc_s[cb + 7] + sh_s[cb + 7], 0.f);
        if (ADD) {
            const float4* hp = (const float4*)(hA + (size_t)ar * 128 + cb);
            float4 h0 = hp[0], h1 = hp[1];
            v[0] += h0.x; v[1] += h0.y; v[2] += h0.z; v[3] += h0.w;
            v[4] += h1.x; v[5] += h1.y; v[6] += h1.z; v[7] += h1.w;
        }
        if (owner) {
            float4* hw = (float4*)(hA + (size_t)ar * 128 + cb);
            hw[0] = make_float4(v[0], v[1], v[2], v[3]);
            hw[1] = make_float4(v[4], v[5], v[6], v[7]);
        }
        uint4 pk;
        pk.x = bf16pair(v[0], v[1]); pk.y = bf16pair(v[2], v[3]);
        pk.z = bf16pair(v[4], v[5]); pk.w = bf16pair(v[6], v[7]);
        short8 afrag = *(short8*)&pk;
#pragma unroll
        for (int nt = 0; nt < 8; nt++) {
            short8 bfrag = wb8[(kt * 8 + nt) * 64 + lane];
            acc[nt] = __builtin_amdgcn_mfma_f32_16x16x32_bf16(afrag, bfrag, acc[nt], 0, 0, 0);
        }
    }

#pragma unroll
    for (int nt = 0; nt < 8; nt++)
#pragma unroll
        for (int rr = 0; rr < 4; rr++)
            lds[w][quad * 4 + rr][nt * 16 + mrow] = acc[nt][rr];

    int row = lane >> 2, h = lane & 3;
    int r = rbase + row;
    float vals[32];
    float ps = 0.f, pd = 0.f;
#pragma unroll
    for (int c = 0; c < 32; c++) {
        float v = lds[w][row][h * 32 + c];
        vals[c] = v;
        ps += v * att_s[h * 32 + c];
        pd += v * att_d[h * 32 + c];
    }
    if (r < N_NODES) {
        unsigned* dstp = xpb + (size_t)r * 64 + h * 16;
#pragma unroll
        for (int qq = 0; qq < 4; qq++) {
            uint4 o;
            o.x = bf16pair(vals[qq * 8 + 0], vals[qq * 8 + 1]);
            o.y = bf16pair(vals[qq * 8 + 2], vals[qq * 8 + 3]);
            o.z = bf16pair(vals[qq * 8 + 4], vals[qq * 8 + 5]);
            o.w = bf16pair(vals[qq * 8 + 6], vals[qq * 8 + 7]);
            ((uint4*)dstp)[qq] = o;
        }
        asrc[r * 4 + h] = ps;
        adst[r * 4 + h] = pd;
    }
}

// ---------------------------------------------------------------------------
// Single-pass aggregation with on-the-fly softmax weights (see R10 notes).
// ---------------------------------------------------------------------------
__launch_bounds__(256)
__global__ void node_kernel(const uint2* __restrict__ aecsr, const float* __restrict__ asrc,
                            const float* __restrict__ adst, const int* __restrict__ rowp,
                            const int2* __restrict__ csr, const unsigned* __restrict__ xpb,
                            float* __restrict__ out) {
    int gw = (blockIdx.x * blockDim.x + threadIdx.x) >> 6;
    int lane = threadIdx.x & 63;
    if (gw >= N_NODES) return;
    int sub = lane >> 4;
    int sl  = lane & 15;
    int h   = sl >> 2;
    int beg = rowp[gw], end = rowp[gw + 1];
    const uint4* xp4 = (const uint4*)xpb;
    float adh = adst[gw * 4 + h];

    float a[8];
#pragma unroll
    for (int c = 0; c < 8; c++) a[c] = 0.f;
    float den = 0.f;

#define PROC(JJ)                                                                 \
    {                                                                            \
        int2 se = csr[JJ];                                                       \
        uint2 ae = aecsr[JJ];                                                    \
        unsigned aw = (h & 2) ? ae.y : ae.x;                                     \
        float aeh = __uint_as_float((h & 1) ? (aw & 0xFFFF0000u) : (aw << 16));  \
        float ash = asrc[se.x * 4 + h];                                          \
        uint4 v = xp4[(size_t)se.x * 16 + sl];                                   \
        float lg = ash + adh + aeh;                                              \
        lg = (lg > 0.f) ? lg : 0.2f * lg;                                        \
        float ex = __expf(fminf(lg, 60.f));                                      \
        a[0] += ex * __uint_as_float(v.x << 16);                                 \
        a[1] += ex * __uint_as_float(v.x & 0xFFFF0000u);                         \
        a[2] += ex * __uint_as_float(v.y << 16);                                 \
        a[3] += ex * __uint_as_float(v.y & 0xFFFF0000u);                         \
        a[4] += ex * __uint_as_float(v.z << 16);                                 \
        a[5] += ex * __uint_as_float(v.z & 0xFFFF0000u);                         \
        a[6] += ex * __uint_as_float(v.w << 16);                                 \
        a[7] += ex * __uint_as_float(v.w & 0xFFFF0000u);                         \
        den += ex;                                                               \
    }

    int j = beg + sub;
    for (; j + 12 < end; j += 16) {
        PROC(j); PROC(j + 4); PROC(j + 8); PROC(j + 12);
    }
    for (; j < end; j += 4) PROC(j);
#undef PROC

#pragma unroll
    for (int c = 0; c < 8; c++) {
        a[c] += __shfl_xor(a[c], 16);
        a[c] += __shfl_xor(a[c], 32);
    }
    den += __shfl_xor(den, 16);
    den += __shfl_xor(den, 32);
    float inv = 1.0f / den;
    if (sub == 0) {
        float* op = out + (size_t)gw * 128 + sl * 8;
        ((float4*)op)[0] = make_float4(a[0] * inv, a[1] * inv, a[2] * inv, a[3] * inv);
        ((float4*)op)[1] = make_float4(a[4] * inv, a[5] * inv, a[6] * inv, a[7] * inv);
    }
}

// ---------------------------------------------------------------------------
// BatchNorm statistics; final-layer standalone update (writes outp).
// ---------------------------------------------------------------------------
__launch_bounds__(256)
__global__ void bnstats_kernel(const float* __restrict__ h, float* __restrict__ bnsum,
                               float* __restrict__ bnsum2) {
    __shared__ float ls[256], ls2[256];
    int t = threadIdx.x;
    int c = t & 127, half = t >> 7;
    int r0 = blockIdx.x * 128;
    float s = 0.f, s2 = 0.f;
    int rend = min(r0 + 128, N_NODES);
    for (int r = r0 + half; r < rend; r += 2) {
        float v = h[(size_t)r * 128 + c];
        s += v; s2 += v * v;
    }
    ls[t] = s; ls2[t] = s2;
    __syncthreads();
    if (half == 0) {
        s += ls[t + 128]; s2 += ls2[t + 128];
        atomicAdd(&bnsum[c], s);
        atomicAdd(&bnsum2[c], s2);
    }
}

__launch_bounds__(256)
__global__ void finalupd_kernel(const float* __restrict__ outb, const float* __restrict__ bnsum,
                                const float* __restrict__ bnsum2, const float* __restrict__ gamma,
                                const float* __restrict__ beta, const float* __restrict__ hA,
                                float* __restrict__ dst) {
    __shared__ float sc_s[128], sh_s[128];
    int t = threadIdx.x;
    if (t < 128) {
        float mu = bnsum[t] / (float)N_NODES;
        float var = bnsum2[t] / (float)N_NODES - mu * mu;
        float inv = rsqrtf(var + BN_EPS);
        float g = gamma[t] * inv;
        sc_s[t] = g;
        sh_s[t] = beta[t] - mu * g;
    }
    __syncthreads();
    int i = blockIdx.x * blockDim.x + t;
    if (i >= N_NODES * 32) return;
    int c4 = (i & 31) * 4;
    float4 o = ((const float4*)outb)[i];
    float4 hh = ((const float4*)hA)[i];
    float4 v;
    v.x = fmaxf(o.x * sc_s[c4 + 0] + sh_s[c4 + 0], 0.f) + hh.x;
    v.y = fmaxf(o.y * sc_s[c4 + 1] + sh_s[c4 + 1], 0.f) + hh.y;
    v.z = fmaxf(o.z * sc_s[c4 + 2] + sh_s[c4 + 2], 0.f) + hh.z;
    v.w = fmaxf(o.w * sc_s[c4 + 3] + sh_s[c4 + 3], 0.f) + hh.w;
    ((float4*)dst)[i] = v;
}

// ---------------------------------------------------------------------------
extern "C" void kernel_launch(void* const* d_in, const int* in_sizes, int n_in,
                              void* d_out, int out_size, void* d_ws, size_t ws_size,
                              hipStream_t stream) {
    const float* x          = (const float*)d_in[0];
    const int*   edge_index = (const int*)d_in[1];
    const float* edge_attr  = (const float*)d_in[2];
    const float* Wp         = (const float*)d_in[3];
    const float* bp         = (const float*)d_in[4];
    const float* W          = (const float*)d_in[5];
    const float* We         = (const float*)d_in[6];
    const float* att_src    = (const float*)d_in[7];
    const float* att_dst    = (const float*)d_in[8];
    const float* att_edge   = (const float*)d_in[9];
    // d_in[10] bias: absorbed exactly by training-mode BN -> skipped
    const float* gamma      = (const float*)d_in[11];
    const float* beta       = (const float*)d_in[12];
    float* outp = (float*)d_out;

    const int* ei_src = edge_index;
    const int* ei_dst = edge_index + N_EDGES;

    char* p = (char*)d_ws;
    auto alloc = [&](size_t nbytes) {
        char* r = p;
        p += (nbytes + 255) & ~(size_t)255;
        return r;
    };
    // zero-initialized region: hist | easum | bnsum(4 layers x 256)
    int*   hist     = (int*)alloc((size_t)N_NODES * 4);
    float* easum    = (float*)alloc(16 * 4);
    float* bnsumall = (float*)alloc((size_t)LAYERS * 256 * 4);
    size_t zero_bytes = (char*)(bnsumall + LAYERS * 256) - (char*)hist;

    float* hA       = (float*)alloc((size_t)N_NODES * 128 * 4);
    unsigned* hAb   = (unsigned*)alloc((size_t)N_NODES * 64 * 4);   // bf16x2 (layer-0 A feed)
    unsigned* xpb   = (unsigned*)alloc((size_t)N_NODES * 64 * 4);   // bf16x2 gather payload
    float* outb     = (float*)alloc((size_t)N_NODES * 128 * 4);
    float* asrc     = (float*)alloc((size_t)N_NODES * 4 * 4);
    float* adst     = (float*)alloc((size_t)N_NODES * 4 * 4);
    float* wea_all  = (float*)alloc((LAYERS * 48 + 16) * 4);
    float* aloop    = wea_all + LAYERS * 48;
    unsigned short* wb = (unsigned short*)alloc((size_t)LAYERS * 16384 * 2);
    int* rowp       = (int*)alloc(((size_t)N_NODES + 1) * 4);
    int* cursor     = (int*)alloc((size_t)N_NODES * 4);
    int2* csr       = (int2*)alloc((size_t)N_ETOT * 8);
    uint2* aecsr    = (uint2*)alloc((size_t)LAYERS * N_ETOT * 8);
    int* bsum       = (int*)alloc(256 * 4);
    int* boff       = (int*)alloc(256 * 4);

    (void)hipMemsetAsync(hist, 0, zero_bytes, stream);

    // ---- preamble: CSR build + folded matrices + W pack, fused ----
    pre1_kernel<<<EB + 256 + WB, 256, 0, stream>>>(ei_dst, hist, edge_attr, easum, W, wb);
    blocksum_kernel<<<SCAN_BLK, 256, 0, stream>>>(hist, bsum);
    pre2_kernel<<<2, 256, 0, stream>>>(bsum, boff, rowp, easum, We, att_edge, wea_all, aloop);
    rowp_kernel<<<SCAN_BLK, 256, 0, stream>>>(hist, boff, rowp, cursor);
    pre3_kernel<<<EB + GB, 256, 0, stream>>>(ei_src, ei_dst, cursor, csr, x, Wp, bp, hA, hAb);
    pre4_kernel<<<EB + GB, 256, 0, stream>>>(csr, edge_attr, wea_all, aloop, aecsr,
                                             (const unsigned short*)hAb, wb,
                                             att_src, att_dst, xpb, asrc, adst);

    for (int l = 0; l < LAYERS; l++) {
        float* bnsum  = bnsumall + l * 256;
        float* bnsum2 = bnsum + 128;
        node_kernel<<<(N_NODES + 3) / 4, 256, 0, stream>>>(
            aecsr + (size_t)l * N_ETOT, asrc, adst, rowp, csr, xpb, outb);
        bnstats_kernel<<<(N_NODES + 127) / 128, 256, 0, stream>>>(outb, bnsum, bnsum2);
        if (l < LAYERS - 1) {
            // fused: h_{l+1} = relu(bn_l(outb)) (+ hA if l>0) -> hA, A-frag in-reg
            if (l == 0)
                gemm_fused_kernel<0><<<GB, 256, 0, stream>>>(
                    outb, bnsum, bnsum2, gamma + l * 128, beta + l * 128, hA,
                    wb + (size_t)(l + 1) * 16384, att_src + (l + 1) * 128,
                    att_dst + (l + 1) * 128, xpb, asrc, adst);
            else
                gemm_fused_kernel<1><<<GB, 256, 0, stream>>>(
                    outb, bnsum, bnsum2, gamma + l * 128, beta + l * 128, hA,
                    wb + (size_t)(l + 1) * 16384, att_src + (l + 1) * 128,
                    att_dst + (l + 1) * 128, xpb, asrc, adst);
        } else {
            finalupd_kernel<<<(N_NODES * 32 + 255) / 256, 256, 0, stream>>>(
                outb, bnsum, bnsum2, gamma + l * 128, beta + l * 128, hA, outp);
        }
    }
}